// Round 6
// baseline (756.927 us; speedup 1.0000x reference)
//
#include <hip/hip_runtime.h>
#include <hip/hip_bf16.h>
#include <math.h>

#define E_EDGES 1000000
#define LN_EPS  1e-5f

typedef unsigned short u16;
typedef __bf16 bf16x8 __attribute__((ext_vector_type(8)));
typedef float  f32x16 __attribute__((ext_vector_type(16)));

// Raw block barrier WITHOUT vmcnt drain: LDS is the only cross-wave channel;
// lgkmcnt(0)+s_barrier suffices and leaves prefetched global loads in flight.
// (__syncthreads emits s_waitcnt vmcnt(0) and would kill the pipeline.)
#define BAR_LGKM() do {                                       \
    __builtin_amdgcn_sched_barrier(0);                        \
    asm volatile("s_waitcnt lgkmcnt(0)" ::: "memory");        \
    __builtin_amdgcn_s_barrier();                             \
    __builtin_amdgcn_sched_barrier(0);                        \
} while (0)

__device__ __forceinline__ float lo2f(unsigned d) {
    union { unsigned u; float f; } v; v.u = d << 16; return v.f;
}
__device__ __forceinline__ float hi2f(unsigned d) {
    union { unsigned u; float f; } v; v.u = d & 0xffff0000u; return v.f;
}
__device__ __forceinline__ float bf2f(u16 u) {
    union { unsigned u; float f; } v; v.u = ((unsigned)u) << 16; return v.f;
}
__device__ __forceinline__ unsigned pk2(float lo, float hi) {
    __hip_bfloat162 h = __float22bfloat162_rn(make_float2(lo, hi));
    unsigned r; __builtin_memcpy(&r, &h, 4); return r;
}

// ---------------------------------------------------------------------------
// Weight -> bf16 MFMA B-fragment conversion (one-time, ~132 KB).
// slots 0..7679: layers 1..3 (ks*2+nt)*64+l ; 7680..8191: layer0 (K pad 64);
// 8192..8447: cw1 (K=64, N=32) for the fused head.
// ---------------------------------------------------------------------------
__global__ __launch_bounds__(256) void wconv_kernel(
    const float* __restrict__ wr, const float* __restrict__ w0,
    const float* __restrict__ cw1, u16* __restrict__ wf)
{
    const int s = blockIdx.x * 256 + threadIdx.x;   // 0..8447
    if (s >= 8448) return;
    const int l    = s & 63;
    const int half = l >> 5;
    uint4 pk;
    if (s < 3 * 2560) {
        const int col = ((s >> 6) & 1) * 32 + (l & 31);
        const int L  = s / 2560;
        const int sl = s % 2560;
        const int kb = (sl >> 7) * 16 + half * 8;
        const float* W = wr + L * 320 * 64;
        pk.x = pk2(W[(kb+0)*64+col], W[(kb+1)*64+col]);
        pk.y = pk2(W[(kb+2)*64+col], W[(kb+3)*64+col]);
        pk.z = pk2(W[(kb+4)*64+col], W[(kb+5)*64+col]);
        pk.w = pk2(W[(kb+6)*64+col], W[(kb+7)*64+col]);
    } else if (s < 8192) {
        const int col = ((s >> 6) & 1) * 32 + (l & 31);
        const int sl = s - 3 * 2560;
        const int kb = (sl >> 7) * 16 + half * 8;
        float v[8];
        #pragma unroll
        for (int p = 0; p < 8; ++p) v[p] = (kb + p < 55) ? w0[(kb+p)*64 + col] : 0.f;
        pk.x = pk2(v[0],v[1]); pk.y = pk2(v[2],v[3]);
        pk.z = pk2(v[4],v[5]); pk.w = pk2(v[6],v[7]);
    } else {                                         // cw1 frags (N=32)
        const int sl = s - 8192;                     // 0..255
        const int ks = sl >> 6;
        const int col = l & 31;
        const int kb = ks * 16 + half * 8;
        pk.x = pk2(cw1[(kb+0)*32+col], cw1[(kb+1)*32+col]);
        pk.y = pk2(cw1[(kb+2)*32+col], cw1[(kb+3)*32+col]);
        pk.z = pk2(cw1[(kb+4)*32+col], cw1[(kb+5)*32+col]);
        pk.w = pk2(cw1[(kb+6)*32+col], cw1[(kb+7)*32+col]);
    }
    *(uint4*)&wf[(size_t)s * 8] = pk;
}

// ---------------------------------------------------------------------------
// xprep: x fp32[E][11] (44 B rows) -> xc bf16[E][16] (32 B rows, aligned).
// ---------------------------------------------------------------------------
__global__ __launch_bounds__(256) void xprep_kernel(
    const float* __restrict__ x, u16* __restrict__ xc)
{
    __shared__ float xs[2816];                  // 256 edges * 11 floats
    const int t = threadIdx.x;
    const long long i0 = (long long)blockIdx.x * 704;   // float4 base
    #pragma unroll
    for (int k = 0; k < 3; ++k) {
        const int idx = t + k * 256;
        if (idx < 704 && i0 + idx < 2750000)
            *(float4*)&xs[idx * 4] = ((const float4*)x)[i0 + idx];
    }
    __syncthreads();
    const size_t e = (size_t)blockIdx.x * 256 + t;
    if (e < E_EDGES) {
        const float* r = &xs[t * 11];
        uint4 o0, o1;
        o0.x = pk2(r[0], r[1]);  o0.y = pk2(r[2], r[3]);
        o0.z = pk2(r[4], r[5]);  o0.w = pk2(r[6], r[7]);
        o1.x = pk2(r[8], r[9]);  o1.y = pk2(r[10], 0.f);
        o1.z = 0u;               o1.w = 0u;
        *(uint4*)&xc[e * 16]     = o0;
        *(uint4*)&xc[e * 16 + 8] = o1;
    }
}

// ---------------------------------------------------------------------------
// Layer 0, 32-edge / 128-thread / 2-wave blocks (9.25 KB LDS). R5-verbatim.
// ---------------------------------------------------------------------------
__global__ __launch_bounds__(128, 4) void layer0_mfma(
    const u16* __restrict__ xc, const int* __restrict__ nbr,
    const u16* __restrict__ wf0, const float* __restrict__ bias,
    const float* __restrict__ lng, const float* __restrict__ lnb,
    u16* __restrict__ xout)
{
    __shared__ u16 sm[4608];                 // 9216 B
    u16* afrag = sm;
    u16* raw   = sm + 2048;                  // 32 edges * 5 rows * 16 u16
    const int t  = threadIdx.x;              // 0..127
    const int l  = t & 63;
    const int wv = t >> 6;                   // 0..1 -> nt
    const int e0 = blockIdx.x * 32;          // grid exact: 31250
    const int el = t >> 2, cq = t & 3;

    {   // ---- gather: 4 threads/edge ----
        const size_t e = (size_t)(e0 + el);
        const int4 n = *(const int4*)(nbr + 4 * e);
        const int nj = (cq == 0) ? n.x : (cq == 1) ? n.y : (cq == 2) ? n.z : n.w;
        const u16* nr = xc + (size_t)nj * 16;
        u16* dst = raw + (el * 5 + 1 + cq) * 16;
        *(uint4*)dst       = *(const uint4*)nr;
        *(uint4*)(dst + 8) = *(const uint4*)(nr + 8);
        if (cq == 0) {
            const u16* xr = xc + e * 16;
            u16* od = raw + (el * 5) * 16;
            *(uint4*)od       = *(const uint4*)xr;
            *(uint4*)(od + 8) = *(const uint4*)(xr + 8);
        }
    }
    __syncthreads();

    {   // ---- feature build: thread (el,cq) owns k-range [cq*16, cq*16+16) ----
        const u16* R = raw + el * 80;
        float f[16];
        if (cq == 0) {            // k0..10: x ; k11..15: |a-c|[0..4]
            #pragma unroll
            for (int i = 0; i < 11; ++i) f[i] = bf2f(R[i]);
            #pragma unroll
            for (int i = 0; i < 5; ++i) f[11+i] = fabsf(bf2f(R[16+i]) - bf2f(R[48+i]));
        } else if (cq == 1) {     // k16..21: |a-c|[5..10] ; k22..31: a+c[0..9]
            #pragma unroll
            for (int i = 0; i < 6; ++i) f[i] = fabsf(bf2f(R[16+5+i]) - bf2f(R[48+5+i]));
            #pragma unroll
            for (int i = 0; i < 10; ++i) f[6+i] = bf2f(R[16+i]) + bf2f(R[48+i]);
        } else if (cq == 2) {     // k32: a+c[10]; k33..43: |b-d|; k44..47: b+d[0..3]
            f[0] = bf2f(R[16+10]) + bf2f(R[48+10]);
            #pragma unroll
            for (int i = 0; i < 11; ++i) f[1+i] = fabsf(bf2f(R[32+i]) - bf2f(R[64+i]));
            #pragma unroll
            for (int i = 0; i < 4; ++i) f[12+i] = bf2f(R[32+i]) + bf2f(R[64+i]);
        } else {                  // k48..54: b+d[4..10]; pad
            #pragma unroll
            for (int i = 0; i < 7; ++i) f[i] = bf2f(R[32+4+i]) + bf2f(R[64+4+i]);
            #pragma unroll
            for (int i = 7; i < 16; ++i) f[i] = 0.f;
        }
        #pragma unroll
        for (int hh = 0; hh < 2; ++hh) {
            uint4 pk;
            pk.x = pk2(f[hh*8+0], f[hh*8+1]);
            pk.y = pk2(f[hh*8+2], f[hh*8+3]);
            pk.z = pk2(f[hh*8+4], f[hh*8+5]);
            pk.w = pk2(f[hh*8+6], f[hh*8+7]);
            const int gsw = (el + 32 * hh) ^ cq;      // row(=cq) bank swizzle
            *(uint4*)(afrag + (size_t)(cq * 64 + gsw) * 8) = pk;
        }
    }
    __syncthreads();

    const int nt = wv;
    f32x16 acc = {};
    const u16* bb = wf0 + (size_t)(nt * 64 + l) * 8;
    #pragma unroll
    for (int ks = 0; ks < 4; ++ks) {
        const bf16x8 a8 = *(const bf16x8*)(afrag + (size_t)(ks * 64 + (l ^ ks)) * 8);
        const bf16x8 b8 = *(const bf16x8*)(bb + ks * 1024);
        acc = __builtin_amdgcn_mfma_f32_32x32x16_bf16(a8, b8, acc, 0, 0, 0);
    }
    __syncthreads();

    float* ebuf = (float*)sm;
    {
        const int col  = nt * 32 + (l & 31);
        const int quad = l >> 5;
        const float bc = bias[col];
        #pragma unroll
        for (int r = 0; r < 16; ++r) {
            const int row = (r & 3) + 8 * (r >> 2) + 4 * quad;  // 0..31
            ebuf[row * 68 + col] = acc[r] + bc;
        }
    }
    __syncthreads();

    {
        const float* rp = ebuf + el * 68 + cq * 16;
        float v[16];
        float s = 0.f, qs = 0.f;
        #pragma unroll
        for (int i = 0; i < 16; ++i) { v[i] = rp[i]; s += v[i]; qs += v[i] * v[i]; }
        s  += __shfl_xor(s, 1);  s  += __shfl_xor(s, 2);
        qs += __shfl_xor(qs, 1); qs += __shfl_xor(qs, 2);
        const float mu   = s * (1.f / 64.f);
        const float var  = qs * (1.f / 64.f) - mu * mu;
        const float rinv = rsqrtf(var + LN_EPS);
        const size_t e   = (size_t)(e0 + el);
        u16* outp        = xout + e * 64 + cq * 16;
        #pragma unroll
        for (int h = 0; h < 2; ++h) {
            uint4 o; unsigned* op = (unsigned*)&o;
            #pragma unroll
            for (int i = 0; i < 4; ++i) {
                const int ci = cq * 16 + h * 8 + i * 2;
                const float y0 = fmaxf(fmaf((v[h*8+i*2]   - mu) * rinv, lng[ci],   lnb[ci]),   0.f);
                const float y1 = fmaxf(fmaf((v[h*8+i*2+1] - mu) * rinv, lng[ci+1], lnb[ci+1]), 0.f);
                op[i] = pk2(y0, y1);
            }
            *(uint4*)(outp + h * 8) = o;
        }
    }
}

// ---------------------------------------------------------------------------
// Pipelined-layer helpers.
// ---------------------------------------------------------------------------
struct GRows { uint4 x0,x1,a0,a1,b0,b1,c0,c1,d0,d1; };

__device__ __forceinline__ void rows_issue(
    const u16* __restrict__ xin, const int4 n, size_t e, int cq, GRows& R)
{
    const u16* xr = xin + e * 64           + cq * 16;
    const u16* ar = xin + (size_t)n.x * 64 + cq * 16;
    const u16* br = xin + (size_t)n.y * 64 + cq * 16;
    const u16* cr = xin + (size_t)n.z * 64 + cq * 16;
    const u16* dr = xin + (size_t)n.w * 64 + cq * 16;
    R.x0 = *(const uint4*)xr;  R.x1 = *(const uint4*)(xr + 8);
    R.a0 = *(const uint4*)ar;  R.a1 = *(const uint4*)(ar + 8);
    R.b0 = *(const uint4*)br;  R.b1 = *(const uint4*)(br + 8);
    R.c0 = *(const uint4*)cr;  R.c1 = *(const uint4*)(cr + 8);
    R.d0 = *(const uint4*)dr;  R.d1 = *(const uint4*)(dr + 8);
}

__device__ __forceinline__ void feat_pair(
    const uint4 u, const uint4 w, uint4& gd, uint4& gs)
{   // gd = |u - w| (bf16-packed), gs = u + w
    const unsigned* up = (const unsigned*)&u;
    const unsigned* wp = (const unsigned*)&w;
    unsigned* dp = (unsigned*)&gd;
    unsigned* sp = (unsigned*)&gs;
    #pragma unroll
    for (int i = 0; i < 4; ++i) {
        const float u0 = lo2f(up[i]), u1 = hi2f(up[i]);
        const float w0 = lo2f(wp[i]), w1 = hi2f(wp[i]);
        dp[i] = pk2(u0 - w0, u1 - w1) & 0x7FFF7FFFu;
        sp[i] = pk2(u0 + w0, u1 + w1);
    }
}

__device__ __forceinline__ void pack_c1(
    u16* __restrict__ afrag, int el, int cq, const GRows& R)
{   // g0 = x (ks 0..3), g1 = |a-c| (4..7), g2 = a+c (8..11)
    #pragma unroll
    for (int w8 = 0; w8 < 2; ++w8) {
        const int gsw = (el + 32 * w8) ^ cq;
        uint4 g1, g2;
        feat_pair(w8 ? R.a1 : R.a0, w8 ? R.c1 : R.c0, g1, g2);
        *(uint4*)(afrag + (size_t)(((0*4 + cq) * 64) + gsw) * 8) = w8 ? R.x1 : R.x0;
        *(uint4*)(afrag + (size_t)(((1*4 + cq) * 64) + gsw) * 8) = g1;
        *(uint4*)(afrag + (size_t)(((2*4 + cq) * 64) + gsw) * 8) = g2;
    }
}

__device__ __forceinline__ void pack_c2(
    u16* __restrict__ afrag, int el, int cq, const GRows& R)
{   // g3 = |b-d| (ks 0..3), g4 = b+d (ks 4..7)
    #pragma unroll
    for (int w8 = 0; w8 < 2; ++w8) {
        const int gsw = (el + 32 * w8) ^ cq;
        uint4 g3, g4;
        feat_pair(w8 ? R.b1 : R.b0, w8 ? R.d1 : R.d0, g3, g4);
        *(uint4*)(afrag + (size_t)(((0*4 + cq) * 64) + gsw) * 8) = g3;
        *(uint4*)(afrag + (size_t)(((1*4 + cq) * 64) + gsw) * 8) = g4;
    }
}

// ---------------------------------------------------------------------------
// Layers 1..2 (and 3 in fallback): 128-thread block = 2 waves, 64 edges as
// TWO 32-edge tiles, software-pipelined: tile1's gather flies under tile0's
// MFMAs+epilogue. B-fragments preloaded in regs (no global loads in loop ->
// no vmcnt wait ever drags the prefetch). Raw lgkm barriers only.
// LDS: afrag 12 KB + ebuf 8.7 KB = 21 KB -> 7 blocks/CU. No VGPR cap (R2/R4
// lesson: bounds-induced caps spill staged rows; peak live ~220 < 256).
// ---------------------------------------------------------------------------
__global__ __launch_bounds__(128) void layer_mfma(
    const u16* __restrict__ xin, const int* __restrict__ nbr,
    const u16* __restrict__ wf, const float* __restrict__ bias,
    const float* __restrict__ lng, const float* __restrict__ lnb,
    u16* __restrict__ xout)
{
    __shared__ u16   afrag[12 * 64 * 8];     // 12 KB
    __shared__ float ebuf[32 * 68];          // 8704 B (separate region!)
    const int t  = threadIdx.x;              // 0..127
    const int l  = t & 63;
    const int nt = t >> 6;
    const int e0 = blockIdx.x * 64;
    const int el = t >> 2;                   // 0..31
    const int cq = t & 3;

    // ---- loop-invariant uniforms ----
    unsigned lgpk[8], lbpk[8];               // exact: ln_g = 1, ln_b = 0
    #pragma unroll
    for (int j = 0; j < 4; ++j) {
        const float4 g4 = *(const float4*)(lng + cq * 16 + j * 4);
        const float4 b4 = *(const float4*)(lnb + cq * 16 + j * 4);
        lgpk[j*2] = pk2(g4.x, g4.y); lgpk[j*2+1] = pk2(g4.z, g4.w);
        lbpk[j*2] = pk2(b4.x, b4.y); lbpk[j*2+1] = pk2(b4.z, b4.w);
    }
    const int colc = nt * 32 + (l & 31);
    const float bc = bias[colc];
    bf16x8 breg[20];                         // B in regs: 80 VGPR, loaded once
    {
        const u16* bb = wf + (size_t)(nt * 64 + l) * 8;
        #pragma unroll
        for (int ks = 0; ks < 20; ++ks) breg[ks] = *(const bf16x8*)(bb + ks * 1024);
    }

    // ---- prologue: both nbr rows + tile0 gather ----
    GRows cur, nxt;
    const int4 n1 = *(const int4*)(nbr + 4 * (size_t)(e0 + 32 + el));
    {
        const int4 n0 = *(const int4*)(nbr + 4 * (size_t)(e0 + el));
        rows_issue(xin, n0, (size_t)(e0 + el), cq, cur);
    }

    #pragma unroll
    for (int tt = 0; tt < 2; ++tt) {
        const int eb = e0 + tt * 32;
        pack_c1(afrag, el, cq, cur);
        BAR_LGKM();

        if (tt == 0)                          // prefetch tile1 under MFMAs
            rows_issue(xin, n1, (size_t)(e0 + 32 + el), cq, nxt);

        f32x16 acc = {};
        #pragma unroll
        for (int ks = 0; ks < 12; ++ks) {
            const bf16x8 a8 = *(const bf16x8*)(afrag + (size_t)(ks * 64 + (l ^ (ks & 3))) * 8);
            acc = __builtin_amdgcn_mfma_f32_32x32x16_bf16(a8, breg[ks], acc, 0, 0, 0);
        }
        BAR_LGKM();

        pack_c2(afrag, el, cq, cur);
        BAR_LGKM();

        #pragma unroll
        for (int ks = 0; ks < 8; ++ks) {
            const bf16x8 a8 = *(const bf16x8*)(afrag + (size_t)(ks * 64 + (l ^ (ks & 3))) * 8);
            acc = __builtin_amdgcn_mfma_f32_32x32x16_bf16(a8, breg[12 + ks], acc, 0, 0, 0);
        }

        {   // epilogue transpose (separate ebuf region)
            const int quad = l >> 5;
            #pragma unroll
            for (int r = 0; r < 16; ++r) {
                const int row = (r & 3) + 8 * (r >> 2) + 4 * quad;  // 0..31
                ebuf[row * 68 + colc] = acc[r] + bc;
            }
        }
        BAR_LGKM();

        {   // LN + ReLU + residual -> xout
            const float* rp = ebuf + el * 68 + cq * 16;
            float v[16];
            float s = 0.f, qs = 0.f;
            #pragma unroll
            for (int i = 0; i < 16; ++i) { v[i] = rp[i]; s += v[i]; qs += v[i] * v[i]; }
            s  += __shfl_xor(s, 1);  s  += __shfl_xor(s, 2);
            qs += __shfl_xor(qs, 1); qs += __shfl_xor(qs, 2);
            const float mu   = s * (1.f / 64.f);
            const float var  = qs * (1.f / 64.f) - mu * mu;
            const float rinv = rsqrtf(var + LN_EPS);
            u16* outp = xout + (size_t)(eb + el) * 64 + cq * 16;
            #pragma unroll
            for (int h = 0; h < 2; ++h) {
                const uint4 res = h ? cur.x1 : cur.x0;
                const unsigned* rr = (const unsigned*)&res;
                uint4 o; unsigned* op = (unsigned*)&o;
                #pragma unroll
                for (int i = 0; i < 4; ++i) {
                    const int k = h * 8 + i * 2;
                    const int j = h * 4 + i;
                    const float y0 = fmaxf(fmaf((v[k]   - mu) * rinv, lo2f(lgpk[j]), lo2f(lbpk[j])), 0.f) + lo2f(rr[i]);
                    const float y1 = fmaxf(fmaf((v[k+1] - mu) * rinv, hi2f(lgpk[j]), hi2f(lbpk[j])), 0.f) + hi2f(rr[i]);
                    op[i] = pk2(y0, y1);
                }
                *(uint4*)(outp + h * 8) = o;
            }
        }
        BAR_LGKM();                          // ebuf reads done before next pack

        cur = nxt;                           // unrolled -> register rename
    }
}

// ---------------------------------------------------------------------------
// Layer 3 fused with head, pipelined like layer_mfma.
// LDS: afrag 12 KB + ebuf 8.7 KB + ybuf 4 KB = 24.6 KB -> 6 blocks/CU.
// hbuf2 overlays afrag (dead between MFMA2 reads and next tile's pack).
// ---------------------------------------------------------------------------
__global__ __launch_bounds__(128) void layer_head_mfma(
    const u16* __restrict__ xin, const int* __restrict__ nbr,
    const u16* __restrict__ wf, const float* __restrict__ bias,
    const float* __restrict__ lng, const float* __restrict__ lnb,
    const u16* __restrict__ wfh, const float* __restrict__ cb1,
    const float* __restrict__ cw2, const float* __restrict__ cb2,
    float* __restrict__ out)
{
    __shared__ u16   afrag[12 * 64 * 8];     // 12 KB
    __shared__ float ebuf[32 * 68];          // 8704 B
    __shared__ u16   ybuf[4 * 64 * 8];       // 4 KB
    float* hbuf2 = (float*)afrag;            // 32*33 f32 = 4224 B overlay
    const int t  = threadIdx.x;
    const int l  = t & 63;
    const int nt = t >> 6;
    const int e0 = blockIdx.x * 64;
    const int el = t >> 2;
    const int cq = t & 3;

    unsigned lgpk[8], lbpk[8];
    #pragma unroll
    for (int j = 0; j < 4; ++j) {
        const float4 g4 = *(const float4*)(lng + cq * 16 + j * 4);
        const float4 b4 = *(const float4*)(lnb + cq * 16 + j * 4);
        lgpk[j*2] = pk2(g4.x, g4.y); lgpk[j*2+1] = pk2(g4.z, g4.w);
        lbpk[j*2] = pk2(b4.x, b4.y); lbpk[j*2+1] = pk2(b4.z, b4.w);
    }
    const int colc = nt * 32 + (l & 31);
    const float bc = bias[colc];
    bf16x8 breg[20];
    {
        const u16* bb = wf + (size_t)(nt * 64 + l) * 8;
        #pragma unroll
        for (int ks = 0; ks < 20; ++ks) breg[ks] = *(const bf16x8*)(bb + ks * 1024);
    }
    const int colh = l & 31;
    const float bc1 = cb1[colh];
    const float w2v = cw2[colh];
    const float b2v = cb2[0];
    bf16x8 bfh[4];
    #pragma unroll
    for (int ks = 0; ks < 4; ++ks)
        bfh[ks] = *(const bf16x8*)(wfh + (size_t)(ks * 64 + l) * 8);

    GRows cur, nxt;
    const int4 n1 = *(const int4*)(nbr + 4 * (size_t)(e0 + 32 + el));
    {
        const int4 n0 = *(const int4*)(nbr + 4 * (size_t)(e0 + el));
        rows_issue(xin, n0, (size_t)(e0 + el), cq, cur);
    }

    #pragma unroll
    for (int tt = 0; tt < 2; ++tt) {
        const int eb = e0 + tt * 32;
        pack_c1(afrag, el, cq, cur);
        BAR_LGKM();

        if (tt == 0)
            rows_issue(xin, n1, (size_t)(e0 + 32 + el), cq, nxt);

        f32x16 acc = {};
        #pragma unroll
        for (int ks = 0; ks < 12; ++ks) {
            const bf16x8 a8 = *(const bf16x8*)(afrag + (size_t)(ks * 64 + (l ^ (ks & 3))) * 8);
            acc = __builtin_amdgcn_mfma_f32_32x32x16_bf16(a8, breg[ks], acc, 0, 0, 0);
        }
        BAR_LGKM();

        pack_c2(afrag, el, cq, cur);
        BAR_LGKM();

        #pragma unroll
        for (int ks = 0; ks < 8; ++ks) {
            const bf16x8 a8 = *(const bf16x8*)(afrag + (size_t)(ks * 64 + (l ^ (ks & 3))) * 8);
            acc = __builtin_amdgcn_mfma_f32_32x32x16_bf16(a8, breg[12 + ks], acc, 0, 0, 0);
        }

        {
            const int quad = l >> 5;
            #pragma unroll
            for (int r = 0; r < 16; ++r) {
                const int row = (r & 3) + 8 * (r >> 2) + 4 * quad;
                ebuf[row * 68 + colc] = acc[r] + bc;
            }
        }
        BAR_LGKM();

        {   // LN + ReLU + residual -> y (bf16) -> ybuf in A-frag layout
            const float* rp = ebuf + el * 68 + cq * 16;
            float v[16];
            float s = 0.f, qs = 0.f;
            #pragma unroll
            for (int i = 0; i < 16; ++i) { v[i] = rp[i]; s += v[i]; qs += v[i] * v[i]; }
            s  += __shfl_xor(s, 1);  s  += __shfl_xor(s, 2);
            qs += __shfl_xor(qs, 1); qs += __shfl_xor(qs, 2);
            const float mu   = s * (1.f / 64.f);
            const float var  = qs * (1.f / 64.f) - mu * mu;
            const float rinv = rsqrtf(var + LN_EPS);
            #pragma unroll
            for (int h = 0; h < 2; ++h) {
                const uint4 res = h ? cur.x1 : cur.x0;
                const unsigned* rr = (const unsigned*)&res;
                uint4 o; unsigned* op = (unsigned*)&o;
                #pragma unroll
                for (int i = 0; i < 4; ++i) {
                    const int k = h * 8 + i * 2;
                    const int j = h * 4 + i;
                    const float y0 = fmaxf(fmaf((v[k]   - mu) * rinv, lo2f(lgpk[j]), lo2f(lbpk[j])), 0.f) + lo2f(rr[i]);
                    const float y1 = fmaxf(fmaf((v[k+1] - mu) * rinv, hi2f(lgpk[j]), hi2f(lbpk[j])), 0.f) + hi2f(rr[i]);
                    op[i] = pk2(y0, y1);
                }
                const int gsw = (el + 32 * h) ^ cq;      // bank swizzle (row=cq)
                *(uint4*)(ybuf + (size_t)((cq * 64) + gsw) * 8) = o;
            }
        }
        BAR_LGKM();

        // GEMM2: y(32x64) @ cw1(64x32), wave 0; writes hbuf2 (afrag overlay)
        if (nt == 0) {
            f32x16 a2 = {};
            #pragma unroll
            for (int ks = 0; ks < 4; ++ks) {
                const bf16x8 a8 = *(const bf16x8*)(ybuf + (size_t)((ks * 64) + (l ^ ks)) * 8);
                a2 = __builtin_amdgcn_mfma_f32_32x32x16_bf16(a8, bfh[ks], a2, 0, 0, 0);
            }
            #pragma unroll
            for (int r = 0; r < 16; ++r) {
                const int row = (r & 3) + 8 * (r >> 2) + 4 * (l >> 5);
                hbuf2[row * 33 + colh] = fmaxf(a2[r] + bc1, 0.f) * w2v;
            }
        }
        BAR_LGKM();

        // row-sum -> logits
        if (t < 64) {
            const int edge = t >> 1, part = t & 1;
            const float* rp = hbuf2 + edge * 33 + part * 16;
            float s = 0.f;
            #pragma unroll
            for (int i = 0; i < 16; ++i) s += rp[i];
            s += __shfl_xor(s, 1);
            if (part == 0) out[eb + edge] = s + b2v;
        }
        BAR_LGKM();                          // hbuf2 reads done before next pack

        cur = nxt;
    }
}

// ---------------------------------------------------------------------------
// Standalone head (fallback path when workspace can't hold W-frags).
// ---------------------------------------------------------------------------
__global__ __launch_bounds__(256) void head_mfma(
    const u16* __restrict__ xin,
    const float* __restrict__ cw1, const float* __restrict__ cb1,
    const float* __restrict__ cw2, const float* __restrict__ cb2,
    float* __restrict__ out)
{
    __shared__ float hbuf[4][32 * 33];
    const int t    = threadIdx.x;
    const int l    = t & 63;
    const int wv   = t >> 6;
    const int col  = l & 31;
    const int half = l >> 5;

    bf16x8 bf[4];
    #pragma unroll
    for (int ks = 0; ks < 4; ++ks) {
        const int kb = ks * 16 + half * 8;
        uint4 pk;
        pk.x = pk2(cw1[(kb+0)*32 + col], cw1[(kb+1)*32 + col]);
        pk.y = pk2(cw1[(kb+2)*32 + col], cw1[(kb+3)*32 + col]);
        pk.z = pk2(cw1[(kb+4)*32 + col], cw1[(kb+5)*32 + col]);
        pk.w = pk2(cw1[(kb+6)*32 + col], cw1[(kb+7)*32 + col]);
        __builtin_memcpy(&bf[ks], &pk, 16);
    }
    const float bc = cb1[col];
    const float w2 = cw2[col];
    const float b2 = cb2[0];

    int tile = blockIdx.x * 4 + wv;
    const int valid = tile < (E_EDGES / 32);
    if (!valid) tile = E_EDGES / 32 - 1;
    const size_t e0 = (size_t)tile * 32;
    const u16* xb = xin + (e0 + col) * 64 + half * 8;
    f32x16 acc = {};
    #pragma unroll
    for (int ks = 0; ks < 4; ++ks) {
        const bf16x8 a8 = *(const bf16x8*)(xb + ks * 16);
        acc = __builtin_amdgcn_mfma_f32_32x32x16_bf16(a8, bf[ks], acc, 0, 0, 0);
    }
    float* hb = hbuf[wv];
    #pragma unroll
    for (int r = 0; r < 16; ++r) {
        const int row = (r & 3) + 8 * (r >> 2) + 4 * half;
        hb[row * 33 + col] = fmaxf(acc[r] + bc, 0.f) * w2;
    }
    __syncthreads();
    const int row2 = l >> 1, part = l & 1;
    const float* rp = hb + row2 * 33 + part * 16;
    float s = 0.f;
    #pragma unroll
    for (int i = 0; i < 16; ++i) s += rp[i];
    s += __shfl_xor(s, 1);
    if (valid && part == 0) out[e0 + row2] = s + b2;
}

// ---------------------------------------------------------------------------
extern "C" void kernel_launch(void* const* d_in, const int* in_sizes, int n_in,
                              void* d_out, int out_size, void* d_ws, size_t ws_size,
                              hipStream_t stream)
{
    (void)in_sizes; (void)n_in; (void)out_size;
    const float* x   = (const float*)d_in[0];
    const int*   nbr = (const int*)d_in[1];
    const float* w0  = (const float*)d_in[2];
    const float* b0  = (const float*)d_in[3];
    const float* wr  = (const float*)d_in[4];
    const float* br  = (const float*)d_in[5];
    const float* lg  = (const float*)d_in[6];
    const float* lb  = (const float*)d_in[7];
    const float* cw1 = (const float*)d_in[8];
    const float* cb1 = (const float*)d_in[9];
    const float* cw2 = (const float*)d_in[10];
    const float* cb2 = (const float*)d_in[11];
    float* out = (float*)d_out;

    u16* xa = (u16*)d_ws;                         // E*64 bf16 = 128e6 B
    u16* xb = xa + (size_t)E_EDGES * 64;          // E*64 bf16 = 128e6 B
    u16* xc = xb;                                 // 32 MB, dead until layer1 writes xb

    const size_t act_bytes = 2ull * E_EDGES * 64 * 2;        // 256e6
    const size_t wf_bytes  = 8448ull * 16;                   // 135168
    const bool fused = (ws_size >= act_bytes + wf_bytes);
    u16* wfrag = fused ? (u16*)((char*)d_ws + act_bytes) : (u16*)d_out;

    const dim3 blk128(128);
    wconv_kernel<<<dim3(33), dim3(256), 0, stream>>>(wr, w0, cw1, wfrag);
    xprep_kernel<<<dim3((E_EDGES + 255) / 256), dim3(256), 0, stream>>>(x, xc);
    layer0_mfma<<<dim3(E_EDGES / 32), blk128, 0, stream>>>(xc, nbr, wfrag + 3*20480, b0, lg, lb, xa);
    layer_mfma<<<dim3(E_EDGES / 64), blk128, 0, stream>>>(xa, nbr, wfrag,         br,       lg + 64,  lb + 64,  xb);
    layer_mfma<<<dim3(E_EDGES / 64), blk128, 0, stream>>>(xb, nbr, wfrag + 20480, br + 64,  lg + 128, lb + 128, xa);
    if (fused) {
        layer_head_mfma<<<dim3(E_EDGES / 64), blk128, 0, stream>>>(
            xa, nbr, wfrag + 40960, br + 128, lg + 192, lb + 192,
            wfrag + 65536, cb1, cw2, cb2, out);
    } else {
        layer_mfma<<<dim3(E_EDGES / 64), blk128, 0, stream>>>(xa, nbr, wfrag + 40960,
            br + 128, lg + 192, lb + 192, xb);
        head_mfma<<<dim3((E_EDGES / 32 + 3) / 4), dim3(256), 0, stream>>>(xb, cw1, cb1, cw2, cb2, out);
    }
}

// Round 7
// 609.062 us; speedup vs baseline: 1.2428x; 1.2428x over previous
//
#include <hip/hip_runtime.h>
#include <hip/hip_bf16.h>
#include <math.h>

#define E_EDGES 1000000
#define LN_EPS  1e-5f

typedef unsigned short u16;
typedef __bf16 bf16x8 __attribute__((ext_vector_type(8)));
typedef float  f32x16 __attribute__((ext_vector_type(16)));
typedef unsigned uv4 __attribute__((ext_vector_type(4)));
typedef int      iv4 __attribute__((ext_vector_type(4)));
typedef float    fv4 __attribute__((ext_vector_type(4)));

__device__ __forceinline__ float lo2f(unsigned d) {
    union { unsigned u; float f; } v; v.u = d << 16; return v.f;
}
__device__ __forceinline__ float hi2f(unsigned d) {
    union { unsigned u; float f; } v; v.u = d & 0xffff0000u; return v.f;
}
__device__ __forceinline__ float bf2f(u16 u) {
    union { unsigned u; float f; } v; v.u = ((unsigned)u) << 16; return v.f;
}
__device__ __forceinline__ unsigned pk2(float lo, float hi) {
    __hip_bfloat162 h = __float22bfloat162_rn(make_float2(lo, hi));
    unsigned r; __builtin_memcpy(&r, &h, 4); return r;
}
// Non-temporal helpers: keep write streams / read-once streams out of L3 so
// the 128 MB activation gather-table stays resident (L3 = 256 MB; without
// this, table + write-stream + nbr = ~270 MB thrash).
__device__ __forceinline__ void nt_store16(u16* p, uint4 v) {
    uv4 w; __builtin_memcpy(&w, &v, 16);
    __builtin_nontemporal_store(w, (uv4*)p);
}
__device__ __forceinline__ int4 nt_load_i4(const int* p) {
    iv4 w = __builtin_nontemporal_load((const iv4*)p);
    int4 r; __builtin_memcpy(&r, &w, 16); return r;
}
__device__ __forceinline__ float4 nt_load_f4(const float4* p) {
    fv4 w = __builtin_nontemporal_load((const fv4*)p);
    float4 r; __builtin_memcpy(&r, &w, 16); return r;
}

// ---------------------------------------------------------------------------
// Weight -> bf16 MFMA B-fragment conversion (one-time, ~132 KB).
// slots 0..7679: layers 1..3 (ks*2+nt)*64+l ; 7680..8191: layer0 (K pad 64);
// 8192..8447: cw1 (K=64, N=32) for the fused head.
// ---------------------------------------------------------------------------
__global__ __launch_bounds__(256) void wconv_kernel(
    const float* __restrict__ wr, const float* __restrict__ w0,
    const float* __restrict__ cw1, u16* __restrict__ wf)
{
    const int s = blockIdx.x * 256 + threadIdx.x;   // 0..8447
    if (s >= 8448) return;
    const int l    = s & 63;
    const int half = l >> 5;
    uint4 pk;
    if (s < 3 * 2560) {
        const int col = ((s >> 6) & 1) * 32 + (l & 31);
        const int L  = s / 2560;
        const int sl = s % 2560;
        const int kb = (sl >> 7) * 16 + half * 8;
        const float* W = wr + L * 320 * 64;
        pk.x = pk2(W[(kb+0)*64+col], W[(kb+1)*64+col]);
        pk.y = pk2(W[(kb+2)*64+col], W[(kb+3)*64+col]);
        pk.z = pk2(W[(kb+4)*64+col], W[(kb+5)*64+col]);
        pk.w = pk2(W[(kb+6)*64+col], W[(kb+7)*64+col]);
    } else if (s < 8192) {
        const int col = ((s >> 6) & 1) * 32 + (l & 31);
        const int sl = s - 3 * 2560;
        const int kb = (sl >> 7) * 16 + half * 8;
        float v[8];
        #pragma unroll
        for (int p = 0; p < 8; ++p) v[p] = (kb + p < 55) ? w0[(kb+p)*64 + col] : 0.f;
        pk.x = pk2(v[0],v[1]); pk.y = pk2(v[2],v[3]);
        pk.z = pk2(v[4],v[5]); pk.w = pk2(v[6],v[7]);
    } else {                                         // cw1 frags (N=32)
        const int sl = s - 8192;                     // 0..255
        const int ks = sl >> 6;
        const int col = l & 31;
        const int kb = ks * 16 + half * 8;
        pk.x = pk2(cw1[(kb+0)*32+col], cw1[(kb+1)*32+col]);
        pk.y = pk2(cw1[(kb+2)*32+col], cw1[(kb+3)*32+col]);
        pk.z = pk2(cw1[(kb+4)*32+col], cw1[(kb+5)*32+col]);
        pk.w = pk2(cw1[(kb+6)*32+col], cw1[(kb+7)*32+col]);
    }
    *(uint4*)&wf[(size_t)s * 8] = pk;
}

// ---------------------------------------------------------------------------
// xprep: x fp32[E][11] (44 B rows, line-crossing) -> xc bf16[E][16]
// (32 B rows, aligned). NT-load the read-once fp32 stream.
// ---------------------------------------------------------------------------
__global__ __launch_bounds__(256) void xprep_kernel(
    const float* __restrict__ x, u16* __restrict__ xc)
{
    __shared__ float xs[2816];                  // 256 edges * 11 floats
    const int t = threadIdx.x;
    const long long i0 = (long long)blockIdx.x * 704;   // float4 base
    #pragma unroll
    for (int k = 0; k < 3; ++k) {
        const int idx = t + k * 256;
        if (idx < 704 && i0 + idx < 2750000)
            *(float4*)&xs[idx * 4] = nt_load_f4(((const float4*)x) + i0 + idx);
    }
    __syncthreads();
    const size_t e = (size_t)blockIdx.x * 256 + t;
    if (e < E_EDGES) {
        const float* r = &xs[t * 11];
        uint4 o0, o1;
        o0.x = pk2(r[0], r[1]);  o0.y = pk2(r[2], r[3]);
        o0.z = pk2(r[4], r[5]);  o0.w = pk2(r[6], r[7]);
        o1.x = pk2(r[8], r[9]);  o1.y = pk2(r[10], 0.f);
        o1.z = 0u;               o1.w = 0u;
        *(uint4*)&xc[e * 16]     = o0;          // keep in cache: layer0 gathers it
        *(uint4*)&xc[e * 16 + 8] = o1;
    }
}

// ---------------------------------------------------------------------------
// Layer 0 (MFMA, K pad 55->64): gather 32-B compact rows -> LDS raw ->
// feature build -> afrag -> GEMM -> LN -> ReLU.  (R3-verbatim + NT hints.)
// ---------------------------------------------------------------------------
__global__ __launch_bounds__(256, 4) void layer0_mfma(
    const u16* __restrict__ xc, const int* __restrict__ nbr,
    const u16* __restrict__ wf0, const float* __restrict__ bias,
    const float* __restrict__ lng, const float* __restrict__ lnb,
    u16* __restrict__ xout)
{
    __shared__ float smem[64 * 68];          // 17.4 KB; first 8 KB = afrag
    __shared__ u16  raw[64 * 5 * 16];        // 10 KB: [edge][slot 0=own,1..4=n]
    u16* afrag = (u16*)smem;
    const int t  = threadIdx.x;
    const int l  = t & 63;
    const int wv = t >> 6;
    const int e0 = blockIdx.x * 64;          // grid exact: 15625
    const int el = t >> 2, cq = t & 3;

    {   // ---- gather: 4 threads/edge, thread j loads neighbor row j ----
        const size_t e = (size_t)(e0 + el);
        const int4 n = nt_load_i4(nbr + 4 * e);
        const int nj = (cq == 0) ? n.x : (cq == 1) ? n.y : (cq == 2) ? n.z : n.w;
        const u16* nr = xc + (size_t)nj * 16;
        u16* dst = raw + (el * 5 + 1 + cq) * 16;
        *(uint4*)dst       = *(const uint4*)nr;
        *(uint4*)(dst + 8) = *(const uint4*)(nr + 8);
        if (cq == 0) {
            const u16* xr = xc + e * 16;
            u16* od = raw + (el * 5) * 16;
            *(uint4*)od       = *(const uint4*)xr;
            *(uint4*)(od + 8) = *(const uint4*)(xr + 8);
        }
    }
    __syncthreads();

    {   // ---- feature build: thread (el,cq) owns k-range [cq*16, cq*16+16) ----
        const u16* R = raw + el * 5 * 16;
        float f[16];
        if (cq == 0) {            // k0..10: x ; k11..15: |a-c|[0..4]
            #pragma unroll
            for (int i = 0; i < 11; ++i) f[i] = bf2f(R[i]);
            #pragma unroll
            for (int i = 0; i < 5; ++i) f[11+i] = fabsf(bf2f(R[16+i]) - bf2f(R[48+i]));
        } else if (cq == 1) {     // k16..21: |a-c|[5..10] ; k22..31: a+c[0..9]
            #pragma unroll
            for (int i = 0; i < 6; ++i) f[i] = fabsf(bf2f(R[16+5+i]) - bf2f(R[48+5+i]));
            #pragma unroll
            for (int i = 0; i < 10; ++i) f[6+i] = bf2f(R[16+i]) + bf2f(R[48+i]);
        } else if (cq == 2) {     // k32: a+c[10]; k33..43: |b-d|; k44..47: b+d[0..3]
            f[0] = bf2f(R[16+10]) + bf2f(R[48+10]);
            #pragma unroll
            for (int i = 0; i < 11; ++i) f[1+i] = fabsf(bf2f(R[32+i]) - bf2f(R[64+i]));
            #pragma unroll
            for (int i = 0; i < 4; ++i) f[12+i] = bf2f(R[32+i]) + bf2f(R[64+i]);
        } else {                  // k48..54: b+d[4..10]; pad
            #pragma unroll
            for (int i = 0; i < 7; ++i) f[i] = bf2f(R[32+4+i]) + bf2f(R[64+4+i]);
            #pragma unroll
            for (int i = 7; i < 16; ++i) f[i] = 0.f;
        }
        const int mt_g  = el >> 5;
        const int lane0 = el & 31;
        u16* abase = afrag + (size_t)mt_g * (4 * 64 * 8);
        #pragma unroll
        for (int hh = 0; hh < 2; ++hh) {
            uint4 pk;
            pk.x = pk2(f[hh*8+0], f[hh*8+1]);
            pk.y = pk2(f[hh*8+2], f[hh*8+3]);
            pk.z = pk2(f[hh*8+4], f[hh*8+5]);
            pk.w = pk2(f[hh*8+6], f[hh*8+7]);
            const int gsw = (lane0 + 32 * hh) ^ cq;   // row(=cq) bank swizzle
            *(uint4*)(abase + (size_t)(cq * 64 + gsw) * 8) = pk;
        }
    }
    __syncthreads();

    const int mt = wv >> 1, nt = wv & 1;
    f32x16 acc = {};
    const u16* ab = afrag + (size_t)mt * (4 * 512);
    const u16* bb = wf0 + (size_t)(nt * 64 + l) * 8;
    #pragma unroll
    for (int ks = 0; ks < 4; ++ks) {
        const bf16x8 a8 = *(const bf16x8*)(ab + (size_t)(ks * 64 + (l ^ ks)) * 8);
        const bf16x8 b8 = *(const bf16x8*)(bb + ks * 1024);
        acc = __builtin_amdgcn_mfma_f32_32x32x16_bf16(a8, b8, acc, 0, 0, 0);
    }
    __syncthreads();

    float* ebuf = smem;
    {
        const int col  = nt * 32 + (l & 31);
        const int quad = l >> 5;
        const float bc = bias[col];
        #pragma unroll
        for (int r = 0; r < 16; ++r) {
            const int row = mt * 32 + (r & 3) + 8 * (r >> 2) + 4 * quad;
            ebuf[row * 68 + col] = acc[r] + bc;
        }
    }
    __syncthreads();

    {
        const float* rp = ebuf + el * 68 + cq * 16;
        float v[16];
        float s = 0.f, qs = 0.f;
        #pragma unroll
        for (int i = 0; i < 16; ++i) { v[i] = rp[i]; s += v[i]; qs += v[i] * v[i]; }
        s  += __shfl_xor(s, 1);  s  += __shfl_xor(s, 2);
        qs += __shfl_xor(qs, 1); qs += __shfl_xor(qs, 2);
        const float mu   = s * (1.f / 64.f);
        const float var  = qs * (1.f / 64.f) - mu * mu;
        const float rinv = rsqrtf(var + LN_EPS);
        const size_t e   = (size_t)(e0 + el);
        u16* outp        = xout + e * 64 + cq * 16;
        #pragma unroll
        for (int h = 0; h < 2; ++h) {
            uint4 o; unsigned* op = (unsigned*)&o;
            #pragma unroll
            for (int i = 0; i < 4; ++i) {
                const int ci = cq * 16 + h * 8 + i * 2;
                const float y0 = fmaxf(fmaf((v[h*8+i*2]   - mu) * rinv, lng[ci],   lnb[ci]),   0.f);
                const float y1 = fmaxf(fmaf((v[h*8+i*2+1] - mu) * rinv, lng[ci+1], lnb[ci+1]), 0.f);
                op[i] = pk2(y0, y1);
            }
            nt_store16(outp + h * 8, o);     // NT: keep L3 for the gather table
        }
    }
}

// ---------------------------------------------------------------------------
// Helpers for the K-streamed layers: feature computation from packed rows.
// ---------------------------------------------------------------------------
__device__ __forceinline__ void feat_pair(
    const uint4 u, const uint4 w, uint4& gd, uint4& gs)
{   // gd = |u - w| (bf16-packed), gs = u + w
    const unsigned* up = (const unsigned*)&u;
    const unsigned* wp = (const unsigned*)&w;
    unsigned* dp = (unsigned*)&gd;
    unsigned* sp = (unsigned*)&gs;
    #pragma unroll
    for (int i = 0; i < 4; ++i) {
        const float u0 = lo2f(up[i]), u1 = hi2f(up[i]);
        const float w0 = lo2f(wp[i]), w1 = hi2f(wp[i]);
        dp[i] = pk2(u0 - w0, u1 - w1) & 0x7FFF7FFFu;
        sp[i] = pk2(u0 + w0, u1 + w1);
    }
}

// ---------------------------------------------------------------------------
// Layers 1..2 (and 3 in fallback): K-streamed A-tile (12 ks + 8 ks chunks)
// in a 24 KB region.  R3-verbatim + NT store/nbr-load.
// ---------------------------------------------------------------------------
__global__ __launch_bounds__(256, 4) void layer_mfma(
    const u16* __restrict__ xin, const int* __restrict__ nbr,
    const u16* __restrict__ wf, const float* __restrict__ bias,
    const float* __restrict__ lng, const float* __restrict__ lnb,
    u16* __restrict__ xout)
{
    __shared__ u16 afrag[2 * 12 * 64 * 8];   // 24 KB (12 ks per mt-half)
    const int t  = threadIdx.x;
    const int l  = t & 63;
    const int wv = t >> 6;
    const int e0 = blockIdx.x * 64;
    const int el = t >> 2;
    const int cq = t & 3;
    const int mt = wv >> 1, nt = wv & 1;

    // ---- gather: all 10 row-halves issued up front (max MLP) ----
    const size_t e = (size_t)(e0 + el);
    const int4 n = nt_load_i4(nbr + 4 * e);
    const u16* xr = xin + e * 64           + cq * 16;
    const u16* ar = xin + (size_t)n.x * 64 + cq * 16;
    const u16* br = xin + (size_t)n.y * 64 + cq * 16;
    const u16* cr = xin + (size_t)n.z * 64 + cq * 16;
    const u16* dr = xin + (size_t)n.w * 64 + cq * 16;
    const uint4 xv0 = *(const uint4*)(xr);     const uint4 xv1 = *(const uint4*)(xr + 8);
    const uint4 av0 = *(const uint4*)(ar);     const uint4 av1 = *(const uint4*)(ar + 8);
    const uint4 bv0 = *(const uint4*)(br);     const uint4 bv1 = *(const uint4*)(br + 8);
    const uint4 cv0 = *(const uint4*)(cr);     const uint4 cv1 = *(const uint4*)(cr + 8);
    const uint4 dv0 = *(const uint4*)(dr);     const uint4 dv1 = *(const uint4*)(dr + 8);

    const int mt_g  = el >> 5;
    const int lane0 = el & 31;
    u16* abase = afrag + (size_t)mt_g * (12 * 512);

    {   // ---- pack chunk 1: g0 = x (slots 0..3), g1 = |a-c| (4..7), g2 = a+c (8..11)
        #pragma unroll
        for (int w8 = 0; w8 < 2; ++w8) {
            const int gsw = (lane0 + 32 * w8) ^ cq;
            uint4 g1, g2;
            feat_pair(w8 ? av1 : av0, w8 ? cv1 : cv0, g1, g2);
            *(uint4*)(abase + (size_t)(((0*4 + cq) * 64) + gsw) * 8) = w8 ? xv1 : xv0;
            *(uint4*)(abase + (size_t)(((1*4 + cq) * 64) + gsw) * 8) = g1;
            *(uint4*)(abase + (size_t)(((2*4 + cq) * 64) + gsw) * 8) = g2;
        }
    }
    __syncthreads();

    f32x16 acc = {};
    const u16* ab = afrag + (size_t)mt * (12 * 512);
    const u16* bb = wf + (size_t)(nt * 64 + l) * 8;
    #pragma unroll
    for (int ks = 0; ks < 12; ++ks) {      // K chunk 1 (b,d rows stay in regs)
        const bf16x8 a8 = *(const bf16x8*)(ab + (size_t)(ks * 64 + (l ^ (ks & 3))) * 8);
        const bf16x8 b8 = *(const bf16x8*)(bb + ks * 1024);
        acc = __builtin_amdgcn_mfma_f32_32x32x16_bf16(a8, b8, acc, 0, 0, 0);
    }
    __syncthreads();

    {   // ---- pack chunk 2: g3 = |b-d| (slots 0..3), g4 = b+d (slots 4..7)
        #pragma unroll
        for (int w8 = 0; w8 < 2; ++w8) {
            const int gsw = (lane0 + 32 * w8) ^ cq;
            uint4 g3, g4;
            feat_pair(w8 ? bv1 : bv0, w8 ? dv1 : dv0, g3, g4);
            *(uint4*)(abase + (size_t)(((0*4 + cq) * 64) + gsw) * 8) = g3;
            *(uint4*)(abase + (size_t)(((1*4 + cq) * 64) + gsw) * 8) = g4;
        }
    }
    __syncthreads();

    #pragma unroll
    for (int ks = 0; ks < 8; ++ks) {       // K chunk 2
        const bf16x8 a8 = *(const bf16x8*)(ab + (size_t)(ks * 64 + (l ^ (ks & 3))) * 8);
        const bf16x8 b8 = *(const bf16x8*)(bb + (12 + ks) * 1024);
        acc = __builtin_amdgcn_mfma_f32_32x32x16_bf16(a8, b8, acc, 0, 0, 0);
    }
    __syncthreads();

    float* ebuf = (float*)afrag;            // 64 x 68 f32 = 17.4 KB <= 24 KB
    {
        const int col  = nt * 32 + (l & 31);
        const int quad = l >> 5;
        const float bc = bias[col];
        #pragma unroll
        for (int r = 0; r < 16; ++r) {
            const int row = mt * 32 + (r & 3) + 8 * (r >> 2) + 4 * quad;
            ebuf[row * 68 + col] = acc[r] + bc;
        }
    }
    __syncthreads();

    {   // ---- LN + ReLU + residual -> xout ----
        float lgv[16], lbv[16];
        #pragma unroll
        for (int j = 0; j < 4; ++j) {
            *(float4*)&lgv[j * 4] = *(const float4*)(lng + cq * 16 + j * 4);
            *(float4*)&lbv[j * 4] = *(const float4*)(lnb + cq * 16 + j * 4);
        }
        const float* rp = ebuf + el * 68 + cq * 16;
        float v[16];
        float s = 0.f, qs = 0.f;
        #pragma unroll
        for (int i = 0; i < 16; ++i) { v[i] = rp[i]; s += v[i]; qs += v[i] * v[i]; }
        s  += __shfl_xor(s, 1);  s  += __shfl_xor(s, 2);
        qs += __shfl_xor(qs, 1); qs += __shfl_xor(qs, 2);
        const float mu   = s * (1.f / 64.f);
        const float var  = qs * (1.f / 64.f) - mu * mu;
        const float rinv = rsqrtf(var + LN_EPS);
        u16* outp        = xout + e * 64 + cq * 16;
        #pragma unroll
        for (int h = 0; h < 2; ++h) {
            const uint4 res = h ? xv1 : xv0;
            const unsigned* rr = (const unsigned*)&res;
            uint4 o; unsigned* op = (unsigned*)&o;
            #pragma unroll
            for (int i = 0; i < 4; ++i) {
                const int k = h * 8 + i * 2;
                const float y0 = fmaxf(fmaf((v[k]   - mu) * rinv, lgv[k],   lbv[k]),   0.f) + lo2f(rr[i]);
                const float y1 = fmaxf(fmaf((v[k+1] - mu) * rinv, lgv[k+1], lbv[k+1]), 0.f) + hi2f(rr[i]);
                op[i] = pk2(y0, y1);
            }
            nt_store16(outp + h * 8, o);    // NT: keep L3 for the gather table
        }
    }
}

// ---------------------------------------------------------------------------
// Layer 3 fused with head, K-streamed (25.6 KB LDS).  R3-verbatim + NT.
// Regions: afrag/ebuf bytes 0..24576 / 0..17408; ybuf bytes 17408..25600;
// hbuf2 overlays bytes 0..8448 after ebuf is consumed.
// ---------------------------------------------------------------------------
__global__ __launch_bounds__(256, 4) void layer_head_mfma(
    const u16* __restrict__ xin, const int* __restrict__ nbr,
    const u16* __restrict__ wf, const float* __restrict__ bias,
    const float* __restrict__ lng, const float* __restrict__ lnb,
    const u16* __restrict__ wfh, const float* __restrict__ cb1,
    const float* __restrict__ cw2, const float* __restrict__ cb2,
    float* __restrict__ out)
{
    __shared__ u16 lds[12800];               // 25.6 KB
    u16*   afrag = lds;
    u16*   ybuf  = lds + 8704;               // bytes 17408..25600 (4096 u16)
    float* hbuf2 = (float*)lds;              // bytes 0..8448 (after ebuf dead)
    const int t  = threadIdx.x;
    const int l  = t & 63;
    const int wv = t >> 6;
    const int e0 = blockIdx.x * 64;
    const int el = t >> 2;
    const int cq = t & 3;
    const int mt = wv >> 1, nt = wv & 1;

    // ---- gather ----
    const size_t e = (size_t)(e0 + el);
    const int4 n = nt_load_i4(nbr + 4 * e);
    const u16* xr = xin + e * 64           + cq * 16;
    const u16* ar = xin + (size_t)n.x * 64 + cq * 16;
    const u16* br = xin + (size_t)n.y * 64 + cq * 16;
    const u16* cr = xin + (size_t)n.z * 64 + cq * 16;
    const u16* dr = xin + (size_t)n.w * 64 + cq * 16;
    const uint4 xv0 = *(const uint4*)(xr);     const uint4 xv1 = *(const uint4*)(xr + 8);
    const uint4 av0 = *(const uint4*)(ar);     const uint4 av1 = *(const uint4*)(ar + 8);
    const uint4 bv0 = *(const uint4*)(br);     const uint4 bv1 = *(const uint4*)(br + 8);
    const uint4 cv0 = *(const uint4*)(cr);     const uint4 cv1 = *(const uint4*)(cr + 8);
    const uint4 dv0 = *(const uint4*)(dr);     const uint4 dv1 = *(const uint4*)(dr + 8);

    const int mt_g  = el >> 5;
    const int lane0 = el & 31;
    u16* abase = afrag + (size_t)mt_g * (12 * 512);

    {   // ---- pack chunk 1 ----
        #pragma unroll
        for (int w8 = 0; w8 < 2; ++w8) {
            const int gsw = (lane0 + 32 * w8) ^ cq;
            uint4 g1, g2;
            feat_pair(w8 ? av1 : av0, w8 ? cv1 : cv0, g1, g2);
            *(uint4*)(abase + (size_t)(((0*4 + cq) * 64) + gsw) * 8) = w8 ? xv1 : xv0;
            *(uint4*)(abase + (size_t)(((1*4 + cq) * 64) + gsw) * 8) = g1;
            *(uint4*)(abase + (size_t)(((2*4 + cq) * 64) + gsw) * 8) = g2;
        }
    }
    __syncthreads();

    f32x16 acc = {};
    const u16* ab = afrag + (size_t)mt * (12 * 512);
    const u16* bb = wf + (size_t)(nt * 64 + l) * 8;
    #pragma unroll
    for (int ks = 0; ks < 12; ++ks) {
        const bf16x8 a8 = *(const bf16x8*)(ab + (size_t)(ks * 64 + (l ^ (ks & 3))) * 8);
        const bf16x8 b8 = *(const bf16x8*)(bb + ks * 1024);
        acc = __builtin_amdgcn_mfma_f32_32x32x16_bf16(a8, b8, acc, 0, 0, 0);
    }
    __syncthreads();

    {   // ---- pack chunk 2 ----
        #pragma unroll
        for (int w8 = 0; w8 < 2; ++w8) {
            const int gsw = (lane0 + 32 * w8) ^ cq;
            uint4 g3, g4;
            feat_pair(w8 ? bv1 : bv0, w8 ? dv1 : dv0, g3, g4);
            *(uint4*)(abase + (size_t)(((0*4 + cq) * 64) + gsw) * 8) = g3;
            *(uint4*)(abase + (size_t)(((1*4 + cq) * 64) + gsw) * 8) = g4;
        }
    }
    __syncthreads();

    #pragma unroll
    for (int ks = 0; ks < 8; ++ks) {
        const bf16x8 a8 = *(const bf16x8*)(ab + (size_t)(ks * 64 + (l ^ (ks & 3))) * 8);
        const bf16x8 b8 = *(const bf16x8*)(bb + (12 + ks) * 1024);
        acc = __builtin_amdgcn_mfma_f32_32x32x16_bf16(a8, b8, acc, 0, 0, 0);
    }
    __syncthreads();

    float* ebuf = (float*)afrag;
    {
        const int col  = nt * 32 + (l & 31);
        const int quad = l >> 5;
        const float bc = bias[col];
        #pragma unroll
        for (int r = 0; r < 16; ++r) {
            const int row = mt * 32 + (r & 3) + 8 * (r >> 2) + 4 * quad;
            ebuf[row * 68 + col] = acc[r] + bc;
        }
    }
    __syncthreads();

    {   // LN + ReLU + residual -> y (bf16) -> ybuf in A-frag layout
        float lgv[16], lbv[16];
        #pragma unroll
        for (int j = 0; j < 4; ++j) {
            *(float4*)&lgv[j * 4] = *(const float4*)(lng + cq * 16 + j * 4);
            *(float4*)&lbv[j * 4] = *(const float4*)(lnb + cq * 16 + j * 4);
        }
        const float* rp = ebuf + el * 68 + cq * 16;
        float v[16];
        float s = 0.f, qs = 0.f;
        #pragma unroll
        for (int i = 0; i < 16; ++i) { v[i] = rp[i]; s += v[i]; qs += v[i] * v[i]; }
        s  += __shfl_xor(s, 1);  s  += __shfl_xor(s, 2);
        qs += __shfl_xor(qs, 1); qs += __shfl_xor(qs, 2);
        const float mu   = s * (1.f / 64.f);
        const float var  = qs * (1.f / 64.f) - mu * mu;
        const float rinv = rsqrtf(var + LN_EPS);
        #pragma unroll
        for (int h = 0; h < 2; ++h) {
            const uint4 res = h ? xv1 : xv0;
            const unsigned* rr = (const unsigned*)&res;
            uint4 o; unsigned* op = (unsigned*)&o;
            #pragma unroll
            for (int i = 0; i < 4; ++i) {
                const int k = h * 8 + i * 2;
                const float y0 = fmaxf(fmaf((v[k]   - mu) * rinv, lgv[k],   lbv[k]),   0.f) + lo2f(rr[i]);
                const float y1 = fmaxf(fmaf((v[k+1] - mu) * rinv, lgv[k+1], lbv[k+1]), 0.f) + hi2f(rr[i]);
                op[i] = pk2(y0, y1);
            }
            const int gsw = (lane0 + 32 * h) ^ cq;   // bank swizzle (row=cq)
            *(uint4*)(ybuf + (size_t)(((mt_g * 4 + cq) * 64) + gsw) * 8) = o;
        }
    }
    __syncthreads();

    // ---- GEMM2: y(64x64) @ cw1(64x32), waves 0..1 ----
    if (wv < 2) {
        const int mt2 = wv;
        f32x16 a2 = {};
        #pragma unroll
        for (int ks = 0; ks < 4; ++ks) {
            const bf16x8 a8 = *(const bf16x8*)(ybuf + (size_t)(((mt2 * 4 + ks) * 64) + (l ^ ks)) * 8);
            const bf16x8 b8 = *(const bf16x8*)(wfh + (size_t)(ks * 64 + l) * 8);
            a2 = __builtin_amdgcn_mfma_f32_32x32x16_bf16(a8, b8, a2, 0, 0, 0);
        }
        const int col = l & 31;
        const float bc1 = cb1[col];
        const float w2v = cw2[col];
        float* hb = hbuf2 + mt2 * (32 * 33);
        #pragma unroll
        for (int r = 0; r < 16; ++r) {
            const int row = (r & 3) + 8 * (r >> 2) + 4 * (l >> 5);
            hb[row * 33 + col] = fmaxf(a2[r] + bc1, 0.f) * w2v;
        }
    }
    __syncthreads();

    // ---- row-sum -> logits ----
    if (t < 128) {
        const int edge = t >> 1, part = t & 1;
        const float* rp = hbuf2 + (edge >> 5) * (32 * 33) + (edge & 31) * 33 + part * 16;
        float s = 0.f;
        #pragma unroll
        for (int i = 0; i < 16; ++i) s += rp[i];
        s += __shfl_xor(s, 1);
        if (part == 0) __builtin_nontemporal_store(s + cb2[0], out + e0 + edge);
    }
}

// ---------------------------------------------------------------------------
// Standalone head (fallback path when workspace can't hold W-frags).
// ---------------------------------------------------------------------------
__global__ __launch_bounds__(256) void head_mfma(
    const u16* __restrict__ xin,
    const float* __restrict__ cw1, const float* __restrict__ cb1,
    const float* __restrict__ cw2, const float* __restrict__ cb2,
    float* __restrict__ out)
{
    __shared__ float hbuf[4][32 * 33];
    const int t    = threadIdx.x;
    const int l    = t & 63;
    const int wv   = t >> 6;
    const int col  = l & 31;
    const int half = l >> 5;

    bf16x8 bf[4];
    #pragma unroll
    for (int ks = 0; ks < 4; ++ks) {
        const int kb = ks * 16 + half * 8;
        uint4 pk;
        pk.x = pk2(cw1[(kb+0)*32 + col], cw1[(kb+1)*32 + col]);
        pk.y = pk2(cw1[(kb+2)*32 + col], cw1[(kb+3)*32 + col]);
        pk.z = pk2(cw1[(kb+4)*32 + col], cw1[(kb+5)*32 + col]);
        pk.w = pk2(cw1[(kb+6)*32 + col], cw1[(kb+7)*32 + col]);
        __builtin_memcpy(&bf[ks], &pk, 16);
    }
    const float bc = cb1[col];
    const float w2 = cw2[col];
    const float b2 = cb2[0];

    int tile = blockIdx.x * 4 + wv;
    const int valid = tile < (E_EDGES / 32);
    if (!valid) tile = E_EDGES / 32 - 1;
    const size_t e0 = (size_t)tile * 32;
    const u16* xb = xin + (e0 + col) * 64 + half * 8;
    f32x16 acc = {};
    #pragma unroll
    for (int ks = 0; ks < 4; ++ks) {
        const bf16x8 a8 = *(const bf16x8*)(xb + ks * 16);
        acc = __builtin_amdgcn_mfma_f32_32x32x16_bf16(a8, bf[ks], acc, 0, 0, 0);
    }
    float* hb = hbuf[wv];
    #pragma unroll
    for (int r = 0; r < 16; ++r) {
        const int row = (r & 3) + 8 * (r >> 2) + 4 * half;
        hb[row * 33 + col] = fmaxf(acc[r] + bc, 0.f) * w2;
    }
    __syncthreads();
    const int row2 = l >> 1, part = l & 1;
    const float* rp = hb + row2 * 33 + part * 16;
    float s = 0.f;
    #pragma unroll
    for (int i = 0; i < 16; ++i) s += rp[i];
    s += __shfl_xor(s, 1);
    if (valid && part == 0) out[e0 + row2] = s + b2;
}

// ---------------------------------------------------------------------------
extern "C" void kernel_launch(void* const* d_in, const int* in_sizes, int n_in,
                              void* d_out, int out_size, void* d_ws, size_t ws_size,
                              hipStream_t stream)
{
    (void)in_sizes; (void)n_in; (void)out_size;
    const float* x   = (const float*)d_in[0];
    const int*   nbr = (const int*)d_in[1];
    const float* w0  = (const float*)d_in[2];
    const float* b0  = (const float*)d_in[3];
    const float* wr  = (const float*)d_in[4];
    const float* br  = (const float*)d_in[5];
    const float* lg  = (const float*)d_in[6];
    const float* lb  = (const float*)d_in[7];
    const float* cw1 = (const float*)d_in[8];
    const float* cb1 = (const float*)d_in[9];
    const float* cw2 = (const float*)d_in[10];
    const float* cb2 = (const float*)d_in[11];
    float* out = (float*)d_out;

    u16* xa = (u16*)d_ws;                         // E*64 bf16 = 128e6 B
    u16* xb = xa + (size_t)E_EDGES * 64;          // E*64 bf16 = 128e6 B
    u16* xc = xb;                                 // 32 MB, dead until layer1 writes xb

    const size_t act_bytes = 2ull * E_EDGES * 64 * 2;        // 256e6
    const size_t wf_bytes  = 8448ull * 16;                   // 135168
    const bool fused = (ws_size >= act_bytes + wf_bytes);
    u16* wfrag = fused ? (u16*)((char*)d_ws + act_bytes) : (u16*)d_out;

    const dim3 blk(256);
    wconv_kernel<<<dim3(33), blk, 0, stream>>>(wr, w0, cw1, wfrag);
    xprep_kernel<<<dim3((E_EDGES + 255) / 256), blk, 0, stream>>>(x, xc);
    layer0_mfma<<<dim3(E_EDGES / 64), blk, 0, stream>>>(xc, nbr, wfrag + 3*20480, b0, lg, lb, xa);
    layer_mfma<<<dim3(E_EDGES / 64), blk, 0, stream>>>(xa, nbr, wfrag,         br,       lg + 64,  lb + 64,  xb);
    layer_mfma<<<dim3(E_EDGES / 64), blk, 0, stream>>>(xb, nbr, wfrag + 20480, br + 64,  lg + 128, lb + 128, xa);
    if (fused) {
        layer_head_mfma<<<dim3(E_EDGES / 64), blk, 0, stream>>>(
            xa, nbr, wfrag + 40960, br + 128, lg + 192, lb + 192,
            wfrag + 65536, cb1, cw2, cb2, out);
    } else {
        layer_mfma<<<dim3(E_EDGES / 64), blk, 0, stream>>>(xa, nbr, wfrag + 40960,
            br + 128, lg + 192, lb + 192, xb);
        head_mfma<<<dim3((E_EDGES / 32 + 3) / 4), blk, 0, stream>>>(xb, cw1, cb1, cw2, cb2, out);
    }
}

// Round 8
// 584.348 us; speedup vs baseline: 1.2953x; 1.0423x over previous
//
#include <hip/hip_runtime.h>
#include <hip/hip_bf16.h>
#include <math.h>

#define E_EDGES 1000000
#define LN_EPS  1e-5f

typedef unsigned short u16;
typedef __bf16 bf16x8 __attribute__((ext_vector_type(8)));
typedef float  f32x16 __attribute__((ext_vector_type(16)));

__device__ __forceinline__ float lo2f(unsigned d) {
    union { unsigned u; float f; } v; v.u = d << 16; return v.f;
}
__device__ __forceinline__ float hi2f(unsigned d) {
    union { unsigned u; float f; } v; v.u = d & 0xffff0000u; return v.f;
}
__device__ __forceinline__ float bf2f(u16 u) {
    union { unsigned u; float f; } v; v.u = ((unsigned)u) << 16; return v.f;
}
__device__ __forceinline__ unsigned pk2(float lo, float hi) {
    __hip_bfloat162 h = __float22bfloat162_rn(make_float2(lo, hi));
    unsigned r; __builtin_memcpy(&r, &h, 4); return r;
}

// ---------------------------------------------------------------------------
// Weight -> bf16 MFMA B-fragment conversion (one-time, ~132 KB).
// slots 0..7679: layers 1..3 (ks*2+nt)*64+l ; 7680..8191: layer0 (K pad 64);
// 8192..8447: cw1 (K=64, N=32) for the fused head.
// ---------------------------------------------------------------------------
__global__ __launch_bounds__(256) void wconv_kernel(
    const float* __restrict__ wr, const float* __restrict__ w0,
    const float* __restrict__ cw1, u16* __restrict__ wf)
{
    const int s = blockIdx.x * 256 + threadIdx.x;   // 0..8447
    if (s >= 8448) return;
    const int l    = s & 63;
    const int half = l >> 5;
    uint4 pk;
    if (s < 3 * 2560) {
        const int col = ((s >> 6) & 1) * 32 + (l & 31);
        const int L  = s / 2560;
        const int sl = s % 2560;
        const int kb = (sl >> 7) * 16 + half * 8;
        const float* W = wr + L * 320 * 64;
        pk.x = pk2(W[(kb+0)*64+col], W[(kb+1)*64+col]);
        pk.y = pk2(W[(kb+2)*64+col], W[(kb+3)*64+col]);
        pk.z = pk2(W[(kb+4)*64+col], W[(kb+5)*64+col]);
        pk.w = pk2(W[(kb+6)*64+col], W[(kb+7)*64+col]);
    } else if (s < 8192) {
        const int col = ((s >> 6) & 1) * 32 + (l & 31);
        const int sl = s - 3 * 2560;
        const int kb = (sl >> 7) * 16 + half * 8;
        float v[8];
        #pragma unroll
        for (int p = 0; p < 8; ++p) v[p] = (kb + p < 55) ? w0[(kb+p)*64 + col] : 0.f;
        pk.x = pk2(v[0],v[1]); pk.y = pk2(v[2],v[3]);
        pk.z = pk2(v[4],v[5]); pk.w = pk2(v[6],v[7]);
    } else {                                         // cw1 frags (N=32)
        const int sl = s - 8192;                     // 0..255
        const int ks = sl >> 6;
        const int col = l & 31;
        const int kb = ks * 16 + half * 8;
        pk.x = pk2(cw1[(kb+0)*32+col], cw1[(kb+1)*32+col]);
        pk.y = pk2(cw1[(kb+2)*32+col], cw1[(kb+3)*32+col]);
        pk.z = pk2(cw1[(kb+4)*32+col], cw1[(kb+5)*32+col]);
        pk.w = pk2(cw1[(kb+6)*32+col], cw1[(kb+7)*32+col]);
    }
    *(uint4*)&wf[(size_t)s * 8] = pk;
}

// ---------------------------------------------------------------------------
// xprep: x fp32[E][11] (44 B rows, line-crossing) -> xc bf16[E][16]
// (32 B rows, aligned). Makes layer0's gather 4 aligned 32-B requests/edge.
// ---------------------------------------------------------------------------
__global__ __launch_bounds__(256) void xprep_kernel(
    const float* __restrict__ x, u16* __restrict__ xc)
{
    __shared__ float xs[2816];                  // 256 edges * 11 floats
    const int t = threadIdx.x;
    const long long i0 = (long long)blockIdx.x * 704;   // float4 base
    #pragma unroll
    for (int k = 0; k < 3; ++k) {
        const int idx = t + k * 256;
        if (idx < 704 && i0 + idx < 2750000)
            *(float4*)&xs[idx * 4] = ((const float4*)x)[i0 + idx];
    }
    __syncthreads();
    const size_t e = (size_t)blockIdx.x * 256 + t;
    if (e < E_EDGES) {
        const float* r = &xs[t * 11];
        uint4 o0, o1;
        o0.x = pk2(r[0], r[1]);  o0.y = pk2(r[2], r[3]);
        o0.z = pk2(r[4], r[5]);  o0.w = pk2(r[6], r[7]);
        o1.x = pk2(r[8], r[9]);  o1.y = pk2(r[10], 0.f);
        o1.z = 0u;               o1.w = 0u;
        *(uint4*)&xc[e * 16]     = o0;
        *(uint4*)&xc[e * 16 + 8] = o1;
    }
}

// ---------------------------------------------------------------------------
// Layer 0 (MFMA, K pad 55->64): gather 32-B compact rows -> LDS raw ->
// feature build -> afrag -> GEMM -> LN -> ReLU.  (R0-verbatim, 27.6 KB LDS.)
// ---------------------------------------------------------------------------
__global__ __launch_bounds__(256, 4) void layer0_mfma(
    const u16* __restrict__ xc, const int* __restrict__ nbr,
    const u16* __restrict__ wf0, const float* __restrict__ bias,
    const float* __restrict__ lng, const float* __restrict__ lnb,
    u16* __restrict__ xout)
{
    __shared__ float smem[64 * 68];          // 17.4 KB; first 8 KB = afrag
    __shared__ u16  raw[64 * 5 * 16];        // 10 KB: [edge][slot 0=own,1..4=n]
    u16* afrag = (u16*)smem;
    const int t  = threadIdx.x;
    const int l  = t & 63;
    const int wv = t >> 6;
    const int e0 = blockIdx.x * 64;          // grid exact: 15625
    const int el = t >> 2, cq = t & 3;

    {   // ---- gather: 4 threads/edge, thread j loads neighbor row j ----
        const size_t e = (size_t)(e0 + el);
        const int4 n = *(const int4*)(nbr + 4 * e);
        const int nj = (cq == 0) ? n.x : (cq == 1) ? n.y : (cq == 2) ? n.z : n.w;
        const u16* nr = xc + (size_t)nj * 16;
        u16* dst = raw + (el * 5 + 1 + cq) * 16;
        *(uint4*)dst       = *(const uint4*)nr;
        *(uint4*)(dst + 8) = *(const uint4*)(nr + 8);
        if (cq == 0) {
            const u16* xr = xc + e * 16;
            u16* od = raw + (el * 5) * 16;
            *(uint4*)od       = *(const uint4*)xr;
            *(uint4*)(od + 8) = *(const uint4*)(xr + 8);
        }
    }
    __syncthreads();

    {   // ---- feature build: thread (el,cq) owns k-range [cq*16, cq*16+16) ----
        const u16* R = raw + el * 5 * 16;
        float f[16];
        if (cq == 0) {            // k0..10: x ; k11..15: |a-c|[0..4]
            #pragma unroll
            for (int i = 0; i < 11; ++i) f[i] = bf2f(R[i]);
            #pragma unroll
            for (int i = 0; i < 5; ++i) f[11+i] = fabsf(bf2f(R[16+i]) - bf2f(R[48+i]));
        } else if (cq == 1) {     // k16..21: |a-c|[5..10] ; k22..31: a+c[0..9]
            #pragma unroll
            for (int i = 0; i < 6; ++i) f[i] = fabsf(bf2f(R[16+5+i]) - bf2f(R[48+5+i]));
            #pragma unroll
            for (int i = 0; i < 10; ++i) f[6+i] = bf2f(R[16+i]) + bf2f(R[48+i]);
        } else if (cq == 2) {     // k32: a+c[10]; k33..43: |b-d|; k44..47: b+d[0..3]
            f[0] = bf2f(R[16+10]) + bf2f(R[48+10]);
            #pragma unroll
            for (int i = 0; i < 11; ++i) f[1+i] = fabsf(bf2f(R[32+i]) - bf2f(R[64+i]));
            #pragma unroll
            for (int i = 0; i < 4; ++i) f[12+i] = bf2f(R[32+i]) + bf2f(R[64+i]);
        } else {                  // k48..54: b+d[4..10]; pad
            #pragma unroll
            for (int i = 0; i < 7; ++i) f[i] = bf2f(R[32+4+i]) + bf2f(R[64+4+i]);
            #pragma unroll
            for (int i = 7; i < 16; ++i) f[i] = 0.f;
        }
        const int mt_g  = el >> 5;
        const int lane0 = el & 31;
        u16* abase = afrag + (size_t)mt_g * (4 * 64 * 8);
        #pragma unroll
        for (int hh = 0; hh < 2; ++hh) {
            uint4 pk;
            pk.x = pk2(f[hh*8+0], f[hh*8+1]);
            pk.y = pk2(f[hh*8+2], f[hh*8+3]);
            pk.z = pk2(f[hh*8+4], f[hh*8+5]);
            pk.w = pk2(f[hh*8+6], f[hh*8+7]);
            const int gsw = (lane0 + 32 * hh) ^ cq;   // row(=cq) bank swizzle
            *(uint4*)(abase + (size_t)(cq * 64 + gsw) * 8) = pk;
        }
    }
    __syncthreads();

    const int mt = wv >> 1, nt = wv & 1;
    f32x16 acc = {};
    const u16* ab = afrag + (size_t)mt * (4 * 512);
    const u16* bb = wf0 + (size_t)(nt * 64 + l) * 8;
    #pragma unroll
    for (int ks = 0; ks < 4; ++ks) {
        const bf16x8 a8 = *(const bf16x8*)(ab + (size_t)(ks * 64 + (l ^ ks)) * 8);
        const bf16x8 b8 = *(const bf16x8*)(bb + ks * 1024);
        acc = __builtin_amdgcn_mfma_f32_32x32x16_bf16(a8, b8, acc, 0, 0, 0);
    }
    __syncthreads();

    float* ebuf = smem;
    {
        const int col  = nt * 32 + (l & 31);
        const int quad = l >> 5;
        const float bc = bias[col];
        #pragma unroll
        for (int r = 0; r < 16; ++r) {
            const int row = mt * 32 + (r & 3) + 8 * (r >> 2) + 4 * quad;
            ebuf[row * 68 + col] = acc[r] + bc;
        }
    }
    __syncthreads();

    {
        const float* rp = ebuf + el * 68 + cq * 16;
        float v[16];
        float s = 0.f, qs = 0.f;
        #pragma unroll
        for (int i = 0; i < 16; ++i) { v[i] = rp[i]; s += v[i]; qs += v[i] * v[i]; }
        s  += __shfl_xor(s, 1);  s  += __shfl_xor(s, 2);
        qs += __shfl_xor(qs, 1); qs += __shfl_xor(qs, 2);
        const float mu   = s * (1.f / 64.f);
        const float var  = qs * (1.f / 64.f) - mu * mu;
        const float rinv = rsqrtf(var + LN_EPS);
        const size_t e   = (size_t)(e0 + el);
        u16* outp        = xout + e * 64 + cq * 16;
        #pragma unroll
        for (int h = 0; h < 2; ++h) {
            uint4 o; unsigned* op = (unsigned*)&o;
            #pragma unroll
            for (int i = 0; i < 4; ++i) {
                const int ci = cq * 16 + h * 8 + i * 2;
                const float y0 = fmaxf(fmaf((v[h*8+i*2]   - mu) * rinv, lng[ci],   lnb[ci]),   0.f);
                const float y1 = fmaxf(fmaf((v[h*8+i*2+1] - mu) * rinv, lng[ci+1], lnb[ci+1]), 0.f);
                op[i] = pk2(y0, y1);
            }
            *(uint4*)(outp + h * 8) = o;
        }
    }
}

// ---------------------------------------------------------------------------
// Helpers for the K-streamed layers: feature computation from packed rows.
// ---------------------------------------------------------------------------
__device__ __forceinline__ void feat_pair(
    const uint4 u, const uint4 w, uint4& gd, uint4& gs)
{   // gd = |u - w| (bf16-packed), gs = u + w
    const unsigned* up = (const unsigned*)&u;
    const unsigned* wp = (const unsigned*)&w;
    unsigned* dp = (unsigned*)&gd;
    unsigned* sp = (unsigned*)&gs;
    #pragma unroll
    for (int i = 0; i < 4; ++i) {
        const float u0 = lo2f(up[i]), u1 = hi2f(up[i]);
        const float w0 = lo2f(wp[i]), w1 = hi2f(wp[i]);
        dp[i] = pk2(u0 - w0, u1 - w1) & 0x7FFF7FFFu;
        sp[i] = pk2(u0 + w0, u1 + w1);
    }
}

// ---------------------------------------------------------------------------
// Layers 1..2 (and 3 in fallback): K-streamed A-tile (12 ks + 8 ks chunks)
// in a 24 KB region -> 6 blocks/CU (was 40 KB -> 4).  Math/swizzle = R0.
// ---------------------------------------------------------------------------
__global__ __launch_bounds__(256, 4) void layer_mfma(
    const u16* __restrict__ xin, const int* __restrict__ nbr,
    const u16* __restrict__ wf, const float* __restrict__ bias,
    const float* __restrict__ lng, const float* __restrict__ lnb,
    u16* __restrict__ xout)
{
    __shared__ u16 afrag[2 * 12 * 64 * 8];   // 24 KB (12 ks per mt-half)
    const int t  = threadIdx.x;
    const int l  = t & 63;
    const int wv = t >> 6;
    const int e0 = blockIdx.x * 64;
    const int el = t >> 2;
    const int cq = t & 3;
    const int mt = wv >> 1, nt = wv & 1;

    // ---- gather: all 10 row-halves issued up front (max MLP) ----
    const size_t e = (size_t)(e0 + el);
    const int4 n = *(const int4*)(nbr + 4 * e);
    const u16* xr = xin + e * 64           + cq * 16;
    const u16* ar = xin + (size_t)n.x * 64 + cq * 16;
    const u16* br = xin + (size_t)n.y * 64 + cq * 16;
    const u16* cr = xin + (size_t)n.z * 64 + cq * 16;
    const u16* dr = xin + (size_t)n.w * 64 + cq * 16;
    const uint4 xv0 = *(const uint4*)(xr);     const uint4 xv1 = *(const uint4*)(xr + 8);
    const uint4 av0 = *(const uint4*)(ar);     const uint4 av1 = *(const uint4*)(ar + 8);
    const uint4 bv0 = *(const uint4*)(br);     const uint4 bv1 = *(const uint4*)(br + 8);
    const uint4 cv0 = *(const uint4*)(cr);     const uint4 cv1 = *(const uint4*)(cr + 8);
    const uint4 dv0 = *(const uint4*)(dr);     const uint4 dv1 = *(const uint4*)(dr + 8);

    const int mt_g  = el >> 5;
    const int lane0 = el & 31;
    u16* abase = afrag + (size_t)mt_g * (12 * 512);

    {   // ---- pack chunk 1: g0 = x (slots 0..3), g1 = |a-c| (4..7), g2 = a+c (8..11)
        #pragma unroll
        for (int w8 = 0; w8 < 2; ++w8) {
            const int gsw = (lane0 + 32 * w8) ^ cq;
            uint4 g1, g2;
            feat_pair(w8 ? av1 : av0, w8 ? cv1 : cv0, g1, g2);
            *(uint4*)(abase + (size_t)(((0*4 + cq) * 64) + gsw) * 8) = w8 ? xv1 : xv0;
            *(uint4*)(abase + (size_t)(((1*4 + cq) * 64) + gsw) * 8) = g1;
            *(uint4*)(abase + (size_t)(((2*4 + cq) * 64) + gsw) * 8) = g2;
        }
    }
    __syncthreads();

    f32x16 acc = {};
    const u16* ab = afrag + (size_t)mt * (12 * 512);
    const u16* bb = wf + (size_t)(nt * 64 + l) * 8;
    #pragma unroll
    for (int ks = 0; ks < 12; ++ks) {      // K chunk 1 (b,d rows stay in regs)
        const bf16x8 a8 = *(const bf16x8*)(ab + (size_t)(ks * 64 + (l ^ (ks & 3))) * 8);
        const bf16x8 b8 = *(const bf16x8*)(bb + ks * 1024);
        acc = __builtin_amdgcn_mfma_f32_32x32x16_bf16(a8, b8, acc, 0, 0, 0);
    }
    __syncthreads();

    {   // ---- pack chunk 2: g3 = |b-d| (slots 0..3), g4 = b+d (slots 4..7)
        #pragma unroll
        for (int w8 = 0; w8 < 2; ++w8) {
            const int gsw = (lane0 + 32 * w8) ^ cq;
            uint4 g3, g4;
            feat_pair(w8 ? bv1 : bv0, w8 ? dv1 : dv0, g3, g4);
            *(uint4*)(abase + (size_t)(((0*4 + cq) * 64) + gsw) * 8) = g3;
            *(uint4*)(abase + (size_t)(((1*4 + cq) * 64) + gsw) * 8) = g4;
        }
    }
    __syncthreads();

    #pragma unroll
    for (int ks = 0; ks < 8; ++ks) {       // K chunk 2
        const bf16x8 a8 = *(const bf16x8*)(ab + (size_t)(ks * 64 + (l ^ (ks & 3))) * 8);
        const bf16x8 b8 = *(const bf16x8*)(bb + (12 + ks) * 1024);
        acc = __builtin_amdgcn_mfma_f32_32x32x16_bf16(a8, b8, acc, 0, 0, 0);
    }
    __syncthreads();

    float* ebuf = (float*)afrag;            // 64 x 68 f32 = 17.4 KB <= 24 KB
    {
        const int col  = nt * 32 + (l & 31);
        const int quad = l >> 5;
        const float bc = bias[col];
        #pragma unroll
        for (int r = 0; r < 16; ++r) {
            const int row = mt * 32 + (r & 3) + 8 * (r >> 2) + 4 * quad;
            ebuf[row * 68 + col] = acc[r] + bc;
        }
    }
    __syncthreads();

    {   // ---- LN + ReLU + residual -> xout ----
        float lgv[16], lbv[16];
        #pragma unroll
        for (int j = 0; j < 4; ++j) {
            *(float4*)&lgv[j * 4] = *(const float4*)(lng + cq * 16 + j * 4);
            *(float4*)&lbv[j * 4] = *(const float4*)(lnb + cq * 16 + j * 4);
        }
        const float* rp = ebuf + el * 68 + cq * 16;
        float v[16];
        float s = 0.f, qs = 0.f;
        #pragma unroll
        for (int i = 0; i < 16; ++i) { v[i] = rp[i]; s += v[i]; qs += v[i] * v[i]; }
        s  += __shfl_xor(s, 1);  s  += __shfl_xor(s, 2);
        qs += __shfl_xor(qs, 1); qs += __shfl_xor(qs, 2);
        const float mu   = s * (1.f / 64.f);
        const float var  = qs * (1.f / 64.f) - mu * mu;
        const float rinv = rsqrtf(var + LN_EPS);
        u16* outp        = xout + e * 64 + cq * 16;
        #pragma unroll
        for (int h = 0; h < 2; ++h) {
            const uint4 res = h ? xv1 : xv0;
            const unsigned* rr = (const unsigned*)&res;
            uint4 o; unsigned* op = (unsigned*)&o;
            #pragma unroll
            for (int i = 0; i < 4; ++i) {
                const int k = h * 8 + i * 2;
                const float y0 = fmaxf(fmaf((v[k]   - mu) * rinv, lgv[k],   lbv[k]),   0.f) + lo2f(rr[i]);
                const float y1 = fmaxf(fmaf((v[k+1] - mu) * rinv, lgv[k+1], lbv[k+1]), 0.f) + hi2f(rr[i]);
                op[i] = pk2(y0, y1);
            }
            *(uint4*)(outp + h * 8) = o;
        }
    }
}

// ---------------------------------------------------------------------------
// Layer 3 fused with head, K-streamed (25.6 KB LDS -> 6 blocks/CU).
// Regions: afrag/ebuf bytes 0..24576 / 0..17408; ybuf bytes 17408..25600;
// hbuf2 overlays bytes 0..8448 after ebuf is consumed.
// ---------------------------------------------------------------------------
__global__ __launch_bounds__(256, 4) void layer_head_mfma(
    const u16* __restrict__ xin, const int* __restrict__ nbr,
    const u16* __restrict__ wf, const float* __restrict__ bias,
    const float* __restrict__ lng, const float* __restrict__ lnb,
    const u16* __restrict__ wfh, const float* __restrict__ cb1,
    const float* __restrict__ cw2, const float* __restrict__ cb2,
    float* __restrict__ out)
{
    __shared__ u16 lds[12800];               // 25.6 KB
    u16*   afrag = lds;
    u16*   ybuf  = lds + 8704;               // bytes 17408..25600 (4096 u16)
    float* hbuf2 = (float*)lds;              // bytes 0..8448 (after ebuf dead)
    const int t  = threadIdx.x;
    const int l  = t & 63;
    const int wv = t >> 6;
    const int e0 = blockIdx.x * 64;
    const int el = t >> 2;
    const int cq = t & 3;
    const int mt = wv >> 1, nt = wv & 1;

    // ---- gather ----
    const size_t e = (size_t)(e0 + el);
    const int4 n = *(const int4*)(nbr + 4 * e);
    const u16* xr = xin + e * 64           + cq * 16;
    const u16* ar = xin + (size_t)n.x * 64 + cq * 16;
    const u16* br = xin + (size_t)n.y * 64 + cq * 16;
    const u16* cr = xin + (size_t)n.z * 64 + cq * 16;
    const u16* dr = xin + (size_t)n.w * 64 + cq * 16;
    const uint4 xv0 = *(const uint4*)(xr);     const uint4 xv1 = *(const uint4*)(xr + 8);
    const uint4 av0 = *(const uint4*)(ar);     const uint4 av1 = *(const uint4*)(ar + 8);
    const uint4 bv0 = *(const uint4*)(br);     const uint4 bv1 = *(const uint4*)(br + 8);
    const uint4 cv0 = *(const uint4*)(cr);     const uint4 cv1 = *(const uint4*)(cr + 8);
    const uint4 dv0 = *(const uint4*)(dr);     const uint4 dv1 = *(const uint4*)(dr + 8);

    const int mt_g  = el >> 5;
    const int lane0 = el & 31;
    u16* abase = afrag + (size_t)mt_g * (12 * 512);

    {   // ---- pack chunk 1 ----
        #pragma unroll
        for (int w8 = 0; w8 < 2; ++w8) {
            const int gsw = (lane0 + 32 * w8) ^ cq;
            uint4 g1, g2;
            feat_pair(w8 ? av1 : av0, w8 ? cv1 : cv0, g1, g2);
            *(uint4*)(abase + (size_t)(((0*4 + cq) * 64) + gsw) * 8) = w8 ? xv1 : xv0;
            *(uint4*)(abase + (size_t)(((1*4 + cq) * 64) + gsw) * 8) = g1;
            *(uint4*)(abase + (size_t)(((2*4 + cq) * 64) + gsw) * 8) = g2;
        }
    }
    __syncthreads();

    f32x16 acc = {};
    const u16* ab = afrag + (size_t)mt * (12 * 512);
    const u16* bb = wf + (size_t)(nt * 64 + l) * 8;
    #pragma unroll
    for (int ks = 0; ks < 12; ++ks) {
        const bf16x8 a8 = *(const bf16x8*)(ab + (size_t)(ks * 64 + (l ^ (ks & 3))) * 8);
        const bf16x8 b8 = *(const bf16x8*)(bb + ks * 1024);
        acc = __builtin_amdgcn_mfma_f32_32x32x16_bf16(a8, b8, acc, 0, 0, 0);
    }
    __syncthreads();

    {   // ---- pack chunk 2 ----
        #pragma unroll
        for (int w8 = 0; w8 < 2; ++w8) {
            const int gsw = (lane0 + 32 * w8) ^ cq;
            uint4 g3, g4;
            feat_pair(w8 ? bv1 : bv0, w8 ? dv1 : dv0, g3, g4);
            *(uint4*)(abase + (size_t)(((0*4 + cq) * 64) + gsw) * 8) = g3;
            *(uint4*)(abase + (size_t)(((1*4 + cq) * 64) + gsw) * 8) = g4;
        }
    }
    __syncthreads();

    #pragma unroll
    for (int ks = 0; ks < 8; ++ks) {
        const bf16x8 a8 = *(const bf16x8*)(ab + (size_t)(ks * 64 + (l ^ (ks & 3))) * 8);
        const bf16x8 b8 = *(const bf16x8*)(bb + (12 + ks) * 1024);
        acc = __builtin_amdgcn_mfma_f32_32x32x16_bf16(a8, b8, acc, 0, 0, 0);
    }
    __syncthreads();

    float* ebuf = (float*)afrag;
    {
        const int col  = nt * 32 + (l & 31);
        const int quad = l >> 5;
        const float bc = bias[col];
        #pragma unroll
        for (int r = 0; r < 16; ++r) {
            const int row = mt * 32 + (r & 3) + 8 * (r >> 2) + 4 * quad;
            ebuf[row * 68 + col] = acc[r] + bc;
        }
    }
    __syncthreads();

    {   // LN + ReLU + residual -> y (bf16) -> ybuf in A-frag layout
        float lgv[16], lbv[16];
        #pragma unroll
        for (int j = 0; j < 4; ++j) {
            *(float4*)&lgv[j * 4] = *(const float4*)(lng + cq * 16 + j * 4);
            *(float4*)&lbv[j * 4] = *(const float4*)(lnb + cq * 16 + j * 4);
        }
        const float* rp = ebuf + el * 68 + cq * 16;
        float v[16];
        float s = 0.f, qs = 0.f;
        #pragma unroll
        for (int i = 0; i < 16; ++i) { v[i] = rp[i]; s += v[i]; qs += v[i] * v[i]; }
        s  += __shfl_xor(s, 1);  s  += __shfl_xor(s, 2);
        qs += __shfl_xor(qs, 1); qs += __shfl_xor(qs, 2);
        const float mu   = s * (1.f / 64.f);
        const float var  = qs * (1.f / 64.f) - mu * mu;
        const float rinv = rsqrtf(var + LN_EPS);
        #pragma unroll
        for (int h = 0; h < 2; ++h) {
            const uint4 res = h ? xv1 : xv0;
            const unsigned* rr = (const unsigned*)&res;
            uint4 o; unsigned* op = (unsigned*)&o;
            #pragma unroll
            for (int i = 0; i < 4; ++i) {
                const int k = h * 8 + i * 2;
                const float y0 = fmaxf(fmaf((v[k]   - mu) * rinv, lgv[k],   lbv[k]),   0.f) + lo2f(rr[i]);
                const float y1 = fmaxf(fmaf((v[k+1] - mu) * rinv, lgv[k+1], lbv[k+1]), 0.f) + hi2f(rr[i]);
                op[i] = pk2(y0, y1);
            }
            const int gsw = (lane0 + 32 * h) ^ cq;   // bank swizzle (row=cq)
            *(uint4*)(ybuf + (size_t)(((mt_g * 4 + cq) * 64) + gsw) * 8) = o;
        }
    }
    __syncthreads();

    // ---- GEMM2: y(64x64) @ cw1(64x32), waves 0..1 ----
    if (wv < 2) {
        const int mt2 = wv;
        f32x16 a2 = {};
        #pragma unroll
        for (int ks = 0; ks < 4; ++ks) {
            const bf16x8 a8 = *(const bf16x8*)(ybuf + (size_t)(((mt2 * 4 + ks) * 64) + (l ^ ks)) * 8);
            const bf16x8 b8 = *(const bf16x8*)(wfh + (size_t)(ks * 64 + l) * 8);
            a2 = __builtin_amdgcn_mfma_f32_32x32x16_bf16(a8, b8, a2, 0, 0, 0);
        }
        const int col = l & 31;
        const float bc1 = cb1[col];
        const float w2v = cw2[col];
        float* hb = hbuf2 + mt2 * (32 * 33);
        #pragma unroll
        for (int r = 0; r < 16; ++r) {
            const int row = (r & 3) + 8 * (r >> 2) + 4 * (l >> 5);
            hb[row * 33 + col] = fmaxf(a2[r] + bc1, 0.f) * w2v;
        }
    }
    __syncthreads();

    // ---- row-sum -> logits ----
    if (t < 128) {
        const int edge = t >> 1, part = t & 1;
        const float* rp = hbuf2 + (edge >> 5) * (32 * 33) + (edge & 31) * 33 + part * 16;
        float s = 0.f;
        #pragma unroll
        for (int i = 0; i < 16; ++i) s += rp[i];
        s += __shfl_xor(s, 1);
        if (part == 0) out[e0 + edge] = s + cb2[0];
    }
}

// ---------------------------------------------------------------------------
// Standalone head (fallback path when workspace can't hold W-frags).
// ---------------------------------------------------------------------------
__global__ __launch_bounds__(256) void head_mfma(
    const u16* __restrict__ xin,
    const float* __restrict__ cw1, const float* __restrict__ cb1,
    const float* __restrict__ cw2, const float* __restrict__ cb2,
    float* __restrict__ out)
{
    __shared__ float hbuf[4][32 * 33];
    const int t    = threadIdx.x;
    const int l    = t & 63;
    const int wv   = t >> 6;
    const int col  = l & 31;
    const int half = l >> 5;

    bf16x8 bf[4];
    #pragma unroll
    for (int ks = 0; ks < 4; ++ks) {
        const int kb = ks * 16 + half * 8;
        uint4 pk;
        pk.x = pk2(cw1[(kb+0)*32 + col], cw1[(kb+1)*32 + col]);
        pk.y = pk2(cw1[(kb+2)*32 + col], cw1[(kb+3)*32 + col]);
        pk.z = pk2(cw1[(kb+4)*32 + col], cw1[(kb+5)*32 + col]);
        pk.w = pk2(cw1[(kb+6)*32 + col], cw1[(kb+7)*32 + col]);
        __builtin_memcpy(&bf[ks], &pk, 16);
    }
    const float bc = cb1[col];
    const float w2 = cw2[col];
    const float b2 = cb2[0];

    int tile = blockIdx.x * 4 + wv;
    const int valid = tile < (E_EDGES / 32);
    if (!valid) tile = E_EDGES / 32 - 1;
    const size_t e0 = (size_t)tile * 32;
    const u16* xb = xin + (e0 + col) * 64 + half * 8;
    f32x16 acc = {};
    #pragma unroll
    for (int ks = 0; ks < 4; ++ks) {
        const bf16x8 a8 = *(const bf16x8*)(xb + ks * 16);
        acc = __builtin_amdgcn_mfma_f32_32x32x16_bf16(a8, bf[ks], acc, 0, 0, 0);
    }
    float* hb = hbuf[wv];
    #pragma unroll
    for (int r = 0; r < 16; ++r) {
        const int row = (r & 3) + 8 * (r >> 2) + 4 * half;
        hb[row * 33 + col] = fmaxf(acc[r] + bc, 0.f) * w2;
    }
    __syncthreads();
    const int row2 = l >> 1, part = l & 1;
    const float* rp = hb + row2 * 33 + part * 16;
    float s = 0.f;
    #pragma unroll
    for (int i = 0; i < 16; ++i) s += rp[i];
    s += __shfl_xor(s, 1);
    if (valid && part == 0) out[e0 + row2] = s + b2;
}

// ---------------------------------------------------------------------------
extern "C" void kernel_launch(void* const* d_in, const int* in_sizes, int n_in,
                              void* d_out, int out_size, void* d_ws, size_t ws_size,
                              hipStream_t stream)
{
    (void)in_sizes; (void)n_in; (void)out_size;
    const float* x   = (const float*)d_in[0];
    const int*   nbr = (const int*)d_in[1];
    const float* w0  = (const float*)d_in[2];
    const float* b0  = (const float*)d_in[3];
    const float* wr  = (const float*)d_in[4];
    const float* br  = (const float*)d_in[5];
    const float* lg  = (const float*)d_in[6];
    const float* lb  = (const float*)d_in[7];
    const float* cw1 = (const float*)d_in[8];
    const float* cb1 = (const float*)d_in[9];
    const float* cw2 = (const float*)d_in[10];
    const float* cb2 = (const float*)d_in[11];
    float* out = (float*)d_out;

    u16* xa = (u16*)d_ws;                         // E*64 bf16 = 128e6 B
    u16* xb = xa + (size_t)E_EDGES * 64;          // E*64 bf16 = 128e6 B
    u16* xc = xb;                                 // 32 MB, dead until layer1 writes xb

    const size_t act_bytes = 2ull * E_EDGES * 64 * 2;        // 256e6
    const size_t wf_bytes  = 8448ull * 16;                   // 135168
    const bool fused = (ws_size >= act_bytes + wf_bytes);
    u16* wfrag = fused ? (u16*)((char*)d_ws + act_bytes) : (u16*)d_out;

    const dim3 blk(256);
    wconv_kernel<<<dim3(33), blk, 0, stream>>>(wr, w0, cw1, wfrag);
    xprep_kernel<<<dim3((E_EDGES + 255) / 256), blk, 0, stream>>>(x, xc);
    layer0_mfma<<<dim3(E_EDGES / 64), blk, 0, stream>>>(xc, nbr, wfrag + 3*20480, b0, lg, lb, xa);
    layer_mfma<<<dim3(E_EDGES / 64), blk, 0, stream>>>(xa, nbr, wfrag,         br,       lg + 64,  lb + 64,  xb);
    layer_mfma<<<dim3(E_EDGES / 64), blk, 0, stream>>>(xb, nbr, wfrag + 20480, br + 64,  lg + 128, lb + 128, xa);
    if (fused) {
        layer_head_mfma<<<dim3(E_EDGES / 64), blk, 0, stream>>>(
            xa, nbr, wfrag + 40960, br + 128, lg + 192, lb + 192,
            wfrag + 65536, cb1, cw2, cb2, out);
    } else {
        layer_mfma<<<dim3(E_EDGES / 64), blk, 0, stream>>>(xa, nbr, wfrag + 40960,
            br + 128, lg + 192, lb + 192, xb);
        head_mfma<<<dim3((E_EDGES / 32 + 3) / 4), blk, 0, stream>>>(xb, cw1, cb1, cw2, cb2, out);
    }
}